// Round 1
// baseline (244.339 us; speedup 1.0000x reference)
//
#include <hip/hip_runtime.h>
#include <math.h>

// Problem constants
static constexpr int B_  = 2;
static constexpr int T_  = 512;
static constexpr int S_  = 2048;
static constexpr int H_  = 768;
static constexpr int L_  = 32;
static constexpr int NH_ = 12;
static constexpr int HD_ = 64;   // H/NH
static constexpr int IM_ = 3072; // 4*H

typedef __bf16 bf16x8 __attribute__((ext_vector_type(8)));
typedef float  f32x4  __attribute__((ext_vector_type(4)));

__device__ __forceinline__ float bf2f(unsigned short u) {
    return __uint_as_float(((unsigned)u) << 16);
}
__device__ __forceinline__ unsigned short f2bf(float f) {
    unsigned u = __float_as_uint(f);
    u += 0x7fffu + ((u >> 16) & 1u);   // RNE
    return (unsigned short)(u >> 16);
}
__device__ __forceinline__ void gl_lds16(const void* g, void* l) {
    __builtin_amdgcn_global_load_lds((const __attribute__((address_space(1))) void*)g,
                                     (__attribute__((address_space(3))) void*)l, 16, 0, 0);
}

// ---------------------------------------------------------------------------
// k_q: q[i] = dq . Wq[i,:] + bq[i], one wave per row.
// Block 0 additionally normalizes span_masks (int32 vs packed-byte autodetect).
__global__ void k_q(const float* __restrict__ dq, const float* __restrict__ w,
                    const float* __restrict__ b, float* __restrict__ q,
                    const int* __restrict__ raw, int* __restrict__ mout) {
    int wv = threadIdx.x >> 6, lane = threadIdx.x & 63;
    int i = blockIdx.x * 4 + wv;
    const float* row = w + (size_t)i * H_;
    float acc = 0.f;
#pragma unroll
    for (int k = 0; k < 12; ++k) acc += dq[lane + 64 * k] * row[lane + 64 * k];
    for (int m = 32; m; m >>= 1) acc += __shfl_xor(acc, m, 64);
    if (lane == 0) q[i] = acc + b[i];
    if (blockIdx.x == 0) {
        __shared__ int bad;
        if (threadIdx.x == 0) bad = 0;
        __syncthreads();
        for (int t = threadIdx.x; t < 1024; t += 256) {
            int v = raw[t];
            if (v != 0 && v != 1) bad = 1;      // benign race
        }
        __syncthreads();
        int byte_layout = bad;
        const unsigned char* rb = (const unsigned char*)raw;
        for (int t = threadIdx.x; t < B_ * S_; t += 256)
            mout[t] = byte_layout ? (int)rb[t] : raw[t];
    }
}

// Fused: weight casts (blocks < CWB) + Wq_eff (blocks >= CWB).
static constexpr int CWB = 2880;   // = (2*H*H + 2*IM*H)/8/256
__global__ void k_castw(const float* __restrict__ s0, const float* __restrict__ s1,
                        const float* __restrict__ s2, const float* __restrict__ s3,
                        unsigned short* __restrict__ d0, unsigned short* __restrict__ d1,
                        unsigned short* __restrict__ d2, unsigned short* __restrict__ d3,
                        const float* __restrict__ q, const float* __restrict__ wk,
                        float* __restrict__ wq) {
    if (blockIdx.x >= CWB) {
        int i = (blockIdx.x - CWB) * 256 + threadIdx.x;   // 36*256 = 9216 exact
        int n = i / H_, hh = i % H_;
        float acc = 0.f;
        for (int d = 0; d < HD_; ++d)
            acc += q[n * HD_ + d] * wk[(size_t)(H_ + n * HD_ + d) * H_ + hh];
        wq[i] = acc;
        return;
    }
    const long n0 = (long)H_ * H_, n2 = (long)IM_ * H_;
    long gid = (long)(blockIdx.x * 256 + threadIdx.x) * 8;
    const float* s; unsigned short* d; long off;
    if (gid < n0)                { s = s0; d = d0; off = gid; }
    else if (gid < 2 * n0)       { s = s1; d = d1; off = gid - n0; }
    else if (gid < 2 * n0 + n2)  { s = s2; d = d2; off = gid - 2 * n0; }
    else                         { s = s3; d = d3; off = gid - 2 * n0 - n2; }
    float4 f0 = *(const float4*)(s + off);
    float4 f1 = *(const float4*)(s + off + 4);
    uint4 o;
    o.x = (unsigned)f2bf(f0.x) | ((unsigned)f2bf(f0.y) << 16);
    o.y = (unsigned)f2bf(f0.z) | ((unsigned)f2bf(f0.w) << 16);
    o.z = (unsigned)f2bf(f1.x) | ((unsigned)f2bf(f1.y) << 16);
    o.w = (unsigned)f2bf(f1.z) | ((unsigned)f2bf(f1.w) << 16);
    *(uint4*)(d + off) = o;
}

// Fused addpe + stok: one block per token row bt.
__global__ void k_xstok(const float* __restrict__ tr, const float* __restrict__ pe,
                        const float* __restrict__ wq,
                        unsigned short* __restrict__ xbf, float* __restrict__ stok) {
    __shared__ float sx[H_];
    int bt = blockIdx.x, tid = threadIdx.x;
    const float* trow = tr + (size_t)bt * H_;
    const float* prow = pe + (size_t)(bt % T_) * H_;
    if (tid < 192) {
        int h0 = tid * 4;
        float4 a = *(const float4*)(trow + h0);
        float4 p = *(const float4*)(prow + h0);
        float v0 = a.x + p.x, v1 = a.y + p.y, v2 = a.z + p.z, v3 = a.w + p.w;
        sx[h0] = v0; sx[h0 + 1] = v1; sx[h0 + 2] = v2; sx[h0 + 3] = v3;
        uint2 o;
        o.x = (unsigned)f2bf(v0) | ((unsigned)f2bf(v1) << 16);
        o.y = (unsigned)f2bf(v2) | ((unsigned)f2bf(v3) << 16);
        *(uint2*)(xbf + (size_t)bt * H_ + h0) = o;
    }
    __syncthreads();
    int lane = tid & 63, w = tid >> 6;
    float xv[12];
#pragma unroll
    for (int k = 0; k < 12; ++k) xv[k] = sx[lane + 64 * k];
#pragma unroll
    for (int hh = 0; hh < 3; ++hh) {
        int n = w * 3 + hh;
        const float* wr = wq + (size_t)n * H_;
        float acc = 0.f;
#pragma unroll
        for (int k = 0; k < 12; ++k) acc += xv[k] * wr[lane + 64 * k];
        for (int m = 32; m; m >>= 1) acc += __shfl_xor(acc, m, 64);
        if (lane == 0) stok[bt * NH_ + n] = acc;
    }
}

// sum of 4 bf16 partial buffers -> bf16, 8 elems/thread
__global__ void k_castv4(const unsigned short* __restrict__ p, size_t pstr,
                         unsigned short* __restrict__ dst, int n) {
    int i = (blockIdx.x * 256 + threadIdx.x) * 8;
    if (i >= n) return;
    float a[8] = {};
#pragma unroll
    for (int z = 0; z < 4; ++z) {
        uint4 u = *(const uint4*)(p + z * pstr + i);
        a[0] += bf2f((unsigned short)(u.x & 0xffff));
        a[1] += bf2f((unsigned short)(u.x >> 16));
        a[2] += bf2f((unsigned short)(u.y & 0xffff));
        a[3] += bf2f((unsigned short)(u.y >> 16));
        a[4] += bf2f((unsigned short)(u.z & 0xffff));
        a[5] += bf2f((unsigned short)(u.z >> 16));
        a[6] += bf2f((unsigned short)(u.w & 0xffff));
        a[7] += bf2f((unsigned short)(u.w >> 16));
    }
    uint4 o;
    o.x = (unsigned)f2bf(a[0]) | ((unsigned)f2bf(a[1]) << 16);
    o.y = (unsigned)f2bf(a[2]) | ((unsigned)f2bf(a[3]) << 16);
    o.z = (unsigned)f2bf(a[4]) | ((unsigned)f2bf(a[5]) << 16);
    o.w = (unsigned)f2bf(a[6]) | ((unsigned)f2bf(a[7]) << 16);
    *(uint4*)(dst + i) = o;
}

// ---------------------------------------------------------------------------
// bf16 MFMA GEMM (R11 core): shared staging, BK=32, 16 KB LDS, 128x128 tile.
// Kept for the small-K launches (steps 4 and 6) where the grid gives >=3
// blocks/CU and per-block work is tiny.
template <bool RELU, bool SPLIT>
__global__ __launch_bounds__(256)
void gemm_bt(const unsigned short* __restrict__ A, const unsigned short* __restrict__ W,
             const float* __restrict__ bias, unsigned short* __restrict__ Cout,
             int M, int N, int K, int kLen, int TX, int SP) {
    __shared__ unsigned short As[4096];    // 128 rows x 32 cols bf16 = 8 KB
    __shared__ unsigned short Bs[4096];
    const int qx = blockIdx.x & 7, t = blockIdx.x >> 3;
    const int gi = t / TX, x = t - gi * TX;
    const int g = gi * 8 + qx;
    int y, z;
    if (SPLIT) { y = g / SP; z = g - y * SP; } else { y = g; z = 0; }
    const int bm = y * 128, bn = x * 128;
    const int kOff = z * kLen;

    const int tid = threadIdx.x, lane = tid & 63, wid = tid >> 6;   // 0..3
    const int wm = (wid >> 1) * 64, wn = (wid & 1) * 64;
    const int r16 = lane >> 2, c4 = lane & 3;
    const int swc = (c4 ^ ((r16 >> 1) & 3)) * 8;       // element offset in row
    const unsigned short* agp = A + (size_t)(bm + wid * 32 + r16) * K + kOff + swc;
    const unsigned short* bgp = W + (size_t)(bn + wid * 32 + r16) * K + kOff + swc;
    unsigned short* lA = As + wid * 1024;              // wave-uniform bases
    unsigned short* lB = Bs + wid * 1024;

    f32x4 acc[4][4];
#pragma unroll
    for (int i = 0; i < 4; ++i)
#pragma unroll
        for (int j = 0; j < 4; ++j) acc[i][j] = f32x4{0.f, 0.f, 0.f, 0.f};

    const int mrow = lane & 15;
    const int q4 = lane >> 4;                          // frag chunk 0..3
    const int sw = (q4 ^ ((mrow >> 1) & 3)) * 8;
    const int NIT = kLen >> 5;

    for (int it = 0; it < NIT; ++it) {
        const int k0 = it << 5;
        gl_lds16(agp + k0, lA);
        gl_lds16(agp + (size_t)16 * K + k0, lA + 512);
        gl_lds16(bgp + k0, lB);
        gl_lds16(bgp + (size_t)16 * K + k0, lB + 512);
        __syncthreads();                   // drains vmcnt: tile staged
        bf16x8 af[4], bfr[4];
#pragma unroll
        for (int i = 0; i < 4; ++i)
            af[i] = *(const bf16x8*)(As + (wm + i * 16 + mrow) * 32 + sw);
#pragma unroll
        for (int j = 0; j < 4; ++j)
            bfr[j] = *(const bf16x8*)(Bs + (wn + j * 16 + mrow) * 32 + sw);
#pragma unroll
        for (int i = 0; i < 4; ++i)
#pragma unroll
            for (int j = 0; j < 4; ++j)
                acc[i][j] = __builtin_amdgcn_mfma_f32_16x16x32_bf16(af[i], bfr[j], acc[i][j], 0, 0, 0);
        __syncthreads();                   // all waves done reading
    }

    const bool addb = !SPLIT || z == 0;
    unsigned short* outp = SPLIT ? Cout + (size_t)z * M * N : Cout;
    const int lr = (lane >> 4) * 4, lc = lane & 15;
#pragma unroll
    for (int j = 0; j < 4; ++j) {
        int col = bn + wn + j * 16 + lc;
        float bv = addb ? bias[col] : 0.f;
#pragma unroll
        for (int i = 0; i < 4; ++i) {
            int row0 = bm + wm + i * 16 + lr;
#pragma unroll
            for (int r = 0; r < 4; ++r) {
                float v = acc[i][j][r] + bv;
                if (RELU) v = fmaxf(v, 0.f);
                outp[(size_t)(row0 + r) * N + col] = f2bf(v);
            }
        }
    }
}

// ---------------------------------------------------------------------------
// 256x256 8-phase counted-vmcnt GEMM (m201 template, plain HIP).
// 512 thr = 8 waves (2M x 4N), per-wave 128x64 output, BK=64, 128 KB LDS
// double-buffer. Per phase: {ds_read frag subtile || issue 1 half-tile
// global_load_lds -> barrier -> lgkmcnt(0) -> 16 MFMA -> barrier};
// s_waitcnt vmcnt(4) only at phases 4/8 (never drained to 0 in the loop).
// LDS swizzle: chunk ^= (row&7) on 16B chunks of the 128B row, applied on
// the pre-swizzled GLOBAL source + the swizzled READ (linear gl_lds dest).
// Requires: M%256==0, N%256==0, kLen%128==0.
//
// Stage schedule (region-safety verified against read phases):
//   ph1: buf1.B-h1@2t+1   ph2: buf1.A-h1@2t+1   ph3: buf0.B-h0@2t+2
//   ph4: buf0.A-h0@2t+2 [vmcnt(4)]   ph5: buf0.B-h1@2t+2
//   ph6: buf0.A-h1@2t+2   ph7: buf1.B-h0@2t+3   ph8: buf1.A-h0@2t+3 [vmcnt(4)]
// Reads of buf b: ph1/5 {A m0-3, B n0-1}, ph2/6 {B n2-3}, ph3/7 {A m4-7}.
// B regions free after ph2/6, A regions free after ph3/7 => every stage is
// issued at or after its region-free barrier. Tail K-tiles clamped (garbage
// re-stage) so vmcnt counts never change.
#define STG(gp_, lp_, h_, kt_) do {                                           \
    const unsigned short* _g = (gp_) + (size_t)((h_) * 128) * K + (kt_) * 64; \
    unsigned short* _l = (lp_) + (h_) * (128 * 64);                           \
    gl_lds16(_g, _l);                                                         \
    gl_lds16(_g + (size_t)8 * K, _l + 8 * 64);                                \
} while (0)

#define LDF(dst_, mat_, rowoff_, kk_)                                         \
    dst_ = *(const bf16x8*)((const char*)(mat_) + (rowoff_) * 128 + rbase +   \
                            ((kk_) ? c1 : c0))

#define RD_A(mat_, base_) do {                                                \
    LDF(a_[0][0], mat_, (base_) + 0,  0); LDF(a_[0][1], mat_, (base_) + 0,  1); \
    LDF(a_[1][0], mat_, (base_) + 16, 0); LDF(a_[1][1], mat_, (base_) + 16, 1); \
    LDF(a_[2][0], mat_, (base_) + 32, 0); LDF(a_[2][1], mat_, (base_) + 32, 1); \
    LDF(a_[3][0], mat_, (base_) + 48, 0); LDF(a_[3][1], mat_, (base_) + 48, 1); \
} while (0)

#define RD_B(dst_, mat_, base_) do {                                          \
    LDF(dst_[0][0], mat_, (base_) + 0,  0); LDF(dst_[0][1], mat_, (base_) + 0,  1); \
    LDF(dst_[1][0], mat_, (base_) + 16, 0); LDF(dst_[1][1], mat_, (base_) + 16, 1); \
} while (0)

#define QPH(MH_, NH_, B_) do {                                                \
    _Pragma("unroll")                                                         \
    for (int m_ = 0; m_ < 4; ++m_) {                                          \
        _Pragma("unroll")                                                     \
        for (int n_ = 0; n_ < 2; ++n_) {                                      \
            f32x4 c_ = acc[(MH_) * 4 + m_][(NH_) * 2 + n_];                   \
            c_ = __builtin_amdgcn_mfma_f32_16x16x32_bf16(a_[m_][0], B_[n_][0], c_, 0, 0, 0); \
            c_ = __builtin_amdgcn_mfma_f32_16x16x32_bf16(a_[m_][1], B_[n_][1], c_, 0, 0, 0); \
            acc[(MH_) * 4 + m_][(NH_) * 2 + n_] = c_;                         \
        }                                                                     \
    }                                                                         \
} while (0)

#define PH_MID do {                                                           \
    __builtin_amdgcn_s_barrier();                                             \
    asm volatile("s_waitcnt lgkmcnt(0)" ::: "memory");                        \
    __builtin_amdgcn_sched_barrier(0);                                        \
    __builtin_amdgcn_s_setprio(1);                                            \
} while (0)

#define PH_END do {                                                           \
    __builtin_amdgcn_s_setprio(0);                                            \
    __builtin_amdgcn_s_barrier();                                             \
    __builtin_amdgcn_sched_barrier(0);                                        \
} while (0)

#define PH_ENDV do {                                                          \
    __builtin_amdgcn_s_setprio(0);                                            \
    asm volatile("s_waitcnt vmcnt(4)" ::: "memory");                          \
    __builtin_amdgcn_s_barrier();                                             \
    __builtin_amdgcn_sched_barrier(0);                                        \
} while (0)

template <bool RELU, bool SPLIT>
__global__ __launch_bounds__(512)
void gemm256(const unsigned short* __restrict__ A, const unsigned short* __restrict__ W,
             const float* __restrict__ bias, unsigned short* __restrict__ Cout,
             int M, int N, int K, int kLen, int NTt, int SP) {
    // lds[0]=A buf0, lds[1]=B buf0, lds[2]=A buf1, lds[3]=B buf1 (32 KB each)
    __shared__ unsigned short lds[4][256 * 64];
    (void)SP;
    const int MT = M >> 8;
    int bid = blockIdx.x;
    int z = 0, rem = bid;
    if (SPLIT) { int tpz = MT * NTt; z = bid / tpz; rem = bid - z * tpz; }
    const int y = rem / NTt, x = rem - y * NTt;
    const int bm = y * 256, bn = x * 256;
    const int kOff = z * kLen;
    const int NT = kLen >> 6;          // K-tiles of 64
    const int NIT2 = NT >> 1;

    const int tid = threadIdx.x, lane = tid & 63, wid = tid >> 6;   // 0..7
    const int wm = (wid >> 2) * 128, wn = (wid & 3) * 64;
    const int mrow = lane & 15, q4 = lane >> 4;
    const int rbase = mrow * 128;                                   // read row byte base
    const int c0 = (q4 ^ (mrow & 7)) * 16;                          // kk=0 chunk byte
    const int c1 = ((4 + q4) ^ (mrow & 7)) * 16;                    // kk=1 chunk byte

    // staging lane geometry: wave w stages rows [w*16, w*16+16) of each half,
    // 2 loads of 8 rows; global col pre-swizzled so linear LDS dest ends up
    // holding LDS[row][c] = G[row][c ^ (row&7)] (matches read-side XOR).
    const int srow = wid * 16 + (lane >> 3);
    const int gcol = ((lane & 7) ^ ((lane >> 3) & 7)) * 8;
    const unsigned short* agp = A + (size_t)(bm + srow) * K + kOff + gcol;
    const unsigned short* bgp = W + (size_t)(bn + srow) * K + kOff + gcol;
    unsigned short* const aLp0 = lds[0] + wid * 1024;
    unsigned short* const bLp0 = lds[1] + wid * 1024;
    unsigned short* const aLp1 = lds[2] + wid * 1024;
    unsigned short* const bLp1 = lds[3] + wid * 1024;

    f32x4 acc[8][4];
#pragma unroll
    for (int i = 0; i < 8; ++i)
#pragma unroll
        for (int j = 0; j < 4; ++j) acc[i][j] = f32x4{0.f, 0.f, 0.f, 0.f};

    bf16x8 a_[4][2], b0_[2][2], b1_[2][2];

    // Prologue: buf0 complete (8 loads), buf1 B-h0/A-h0 (4 loads, play "ph7/ph8").
    STG(agp, aLp0, 0, 0);
    STG(agp, aLp0, 1, 0);
    STG(bgp, bLp0, 0, 0);
    STG(bgp, bLp0, 1, 0);
    STG(bgp, bLp1, 0, 1);
    STG(agp, aLp1, 0, 1);
    asm volatile("s_waitcnt vmcnt(4)" ::: "memory");   // buf0's 8 landed
    __builtin_amdgcn_s_barrier();
    __builtin_amdgcn_sched_barrier(0);

    for (int t = 0; t < NIT2; ++t) {
        const int k1 = 2 * t + 1;
        int k2 = 2 * t + 2; if (k2 > NT - 1) k2 = NT - 1;
        int k3 = 2 * t + 3; if (k3 > NT - 1) k3 = NT - 1;
        // ---- K-tile 2t (buf0) ----
        RD_A(lds[0], wm);
        RD_B(b0_, lds[1], wn);
        STG(bgp, bLp1, 1, k1);
        PH_MID; QPH(0, 0, b0_); PH_END;                  // ph1
        RD_B(b1_, lds[1], wn + 32);
        STG(agp, aLp1, 1, k1);
        PH_MID; QPH(0, 1, b1_); PH_END;                  // ph2
        RD_A(lds[0], wm + 64);
        STG(bgp, bLp0, 0, k2);
        PH_MID; QPH(1, 0, b0_); PH_END;                  // ph3
        STG(agp, aLp0, 0, k2);
        PH_MID; QPH(1, 1, b1_); PH_ENDV;                 // ph4 (buf1 now landed)
        // ---- K-tile 2t+1 (buf1) ----
        RD_A(lds[2], wm);
        RD_B(b0_, lds[3], wn);
        STG(bgp, bLp0, 1, k2);
        PH_MID; QPH(0, 0, b0_); PH_END;                  // ph5
        RD_B(b1_, lds[3], wn + 32);
        STG(agp, aLp0, 1, k2);
        PH_MID; QPH(0, 1, b1_); PH_END;                  // ph6
        RD_A(lds[2], wm + 64);
        STG(bgp, bLp1, 0, k3);
        PH_MID; QPH(1, 0, b0_); PH_END;                  // ph7
        STG(agp, aLp1, 0, k3);
        PH_MID; QPH(1, 1, b1_); PH_ENDV;                 // ph8 (buf0' landed)
    }

    // epilogue: C/D layout col=lane&15, row=(lane>>4)*4+reg (verified m89/m91)
    const bool addb = !SPLIT || z == 0;
    unsigned short* outp = SPLIT ? Cout + (size_t)z * M * N : Cout;
    const int lr = (lane >> 4) * 4, lc = lane & 15;
#pragma unroll
    for (int j = 0; j < 4; ++j) {
        int col = bn + wn + j * 16 + lc;
        float bv = addb ? bias[col] : 0.f;
#pragma unroll
        for (int i = 0; i < 8; ++i) {
            int row0 = bm + wm + i * 16 + lr;
#pragma unroll
            for (int r = 0; r < 4; ++r) {
                float v = acc[i][j][r] + bv;
                if (RELU) v = fmaxf(v, 0.f);
                outp[(size_t)(row0 + r) * N + col] = f2bf(v);
            }
        }
    }
}

// ---------------------------------------------------------------------------
// Per-span attention pooling
__global__ void k_attn(const float* __restrict__ stok, const unsigned short* __restrict__ vtok,
                       const int* __restrict__ span_ids, const int* __restrict__ masks,
                       unsigned short* __restrict__ ctx) {
    int r = blockIdx.x, b = r / S_;
    unsigned short* out = ctx + (size_t)r * H_;
    int tid = threadIdx.x;
    __shared__ float w[NH_][L_];
    __shared__ int idxs[L_];
    __shared__ int s_len;
    if (tid == 0) {
        int m = masks[r];
        int st = span_ids[2 * r], en = span_ids[2 * r + 1];
        int len = m ? (en - st) : 0;
        len = len < 0 ? 0 : (len > L_ ? L_ : len);
        s_len = len;
    }
    __syncthreads();
    int len = s_len;
    if (len == 0) {
        for (int h2 = tid; h2 < H_ / 2; h2 += 256) ((unsigned*)out)[h2] = 0u;
        return;
    }
    if (tid < L_) {
        int p = span_ids[2 * r] + tid;
        idxs[tid] = p < 0 ? 0 : (p > T_ - 1 ? T_ - 1 : p);
    }
    __syncthreads();
    for (int i = tid; i < NH_ * L_; i += 256) {
        int n = i / L_, l = i % L_;
        w[n][l] = (l < len) ? stok[(size_t)(b * T_ + idxs[l]) * NH_ + n] * 0.125f : -INFINITY;
    }
    __syncthreads();
    if (tid < NH_) {
        float mx = -INFINITY;
        for (int l = 0; l < len; ++l) mx = fmaxf(mx, w[tid][l]);
        float sum = 0.f;
        for (int l = 0; l < len; ++l) { float e = __expf(w[tid][l] - mx); w[tid][l] = e; sum += e; }
        float inv = 1.f / sum;
        for (int l = 0; l < len; ++l) w[tid][l] *= inv;
    }
    __syncthreads();
    if (tid < 192) {
        int h0 = tid * 4, n = h0 >> 6;
        float a0 = 0.f, a1 = 0.f, a2 = 0.f, a3 = 0.f;
        for (int l = 0; l < len; ++l) {
            float wl = w[n][l];
            const unsigned short* vr = vtok + (size_t)(b * T_ + idxs[l]) * H_ + h0;
            uint2 u = *(const uint2*)vr;
            a0 += wl * bf2f((unsigned short)(u.x & 0xffff));
            a1 += wl * bf2f((unsigned short)(u.x >> 16));
            a2 += wl * bf2f((unsigned short)(u.y & 0xffff));
            a3 += wl * bf2f((unsigned short)(u.y >> 16));
        }
        uint2 o;
        o.x = (unsigned)f2bf(a0) | ((unsigned)f2bf(a1) << 16);
        o.y = (unsigned)f2bf(a2) | ((unsigned)f2bf(a3) << 16);
        *(uint2*)(out + h0) = o;
    }
}

// ---------------------------------------------------------------------------
// LayerNorm over (sum of 4 bf16 partials + res).
template <bool RESROW, bool MASKOUT>
__global__ void k_ln(const unsigned short* __restrict__ parts, size_t pstr,
                     const float* __restrict__ resf, const unsigned short* __restrict__ resb,
                     const float* __restrict__ g, const float* __restrict__ bt,
                     float* __restrict__ outf, unsigned short* __restrict__ outb,
                     const int* __restrict__ masks) {
    int r = blockIdx.x;
    int tid = threadIdx.x;
    float v[3];
    float lsum = 0.f;
#pragma unroll
    for (int i = 0; i < 3; ++i) {
        int h = tid + 256 * i;
        float s = RESROW ? bf2f(resb[(size_t)r * H_ + h]) : resf[h];
#pragma unroll
        for (int z = 0; z < 4; ++z)
            s += bf2f(parts[z * pstr + (size_t)r * H_ + h]);
        v[i] = s;
        lsum += s;
    }
    __shared__ float sh[256];
    sh[tid] = lsum;
    __syncthreads();
    for (int st = 128; st > 0; st >>= 1) {
        if (tid < st) sh[tid] += sh[tid + st];
        __syncthreads();
    }
    float mean = sh[0] * (1.f / H_);
    __syncthreads();
    float lvar = 0.f;
#pragma unroll
    for (int i = 0; i < 3; ++i) { float d = v[i] - mean; lvar += d * d; }
    sh[tid] = lvar;
    __syncthreads();
    for (int st = 128; st > 0; st >>= 1) {
        if (tid < st) sh[tid] += sh[tid + st];
        __syncthreads();
    }
    float var = sh[0] * (1.f / H_);
    float scale = rsqrtf(var + 1e-5f);
    float mfac = 1.f;
    if (MASKOUT) mfac = masks[r] ? 1.f : 0.f;
#pragma unroll
    for (int i = 0; i < 3; ++i) {
        int h = tid + 256 * i;
        float o = ((v[i] - mean) * scale * g[h] + bt[h]) * mfac;
        if (MASKOUT) outf[(size_t)r * H_ + h] = o;
        else         outb[(size_t)r * H_ + h] = f2bf(o);
    }
}

// ---------------------------------------------------------------------------
extern "C" void kernel_launch(void* const* d_in, const int* in_sizes, int n_in,
                              void* d_out, int out_size, void* d_ws, size_t ws_size,
                              hipStream_t stream) {
    const float* token_reps = (const float*)d_in[0];
    const int*   span_ids   = (const int*)d_in[1];
    const int*   masks_raw  = (const int*)d_in[2];
    const float* pe   = (const float*)d_in[4];
    const float* dq   = (const float*)d_in[5];
    const float* in_w = (const float*)d_in[6];
    const float* in_b = (const float*)d_in[7];
    const float* ow   = (const float*)d_in[8];
    const float* ob   = (const float*)d_in[9];
    const float* g    = (const float*)d_in[10];
    const float* bt   = (const float*)d_in[11];
    const float* w1   = (const float*)d_in[12];
    const float* b1   = (const float*)d_in[13];
    const float* w2   = (const float*)d_in[14];
    const float* b2   = (const float*)d_in[15];

    const int BS = B_ * S_;        // 4096
    const int BT = B_ * T_;        // 1024

    // Workspace layout
    float* fws   = (float*)d_ws;
    float* stok  = fws;                         // 12288
    float* qv    = stok + BT * NH_;             // 768
    float* wqeff = qv + H_;                     // 9216
    unsigned short* us = (unsigned short*)(wqeff + NH_ * H_);
    unsigned short* pbuf = us;                       // 4 * BS*H
    unsigned short* xbf  = pbuf + (size_t)4 * BS * H_;
    unsigned short* vtok = xbf + (size_t)BT * H_;
    unsigned short* ctx  = vtok + (size_t)BT * H_;
    unsigned short* x1bf = ctx + (size_t)BS * H_;
    unsigned short* f1   = x1bf + (size_t)BS * H_;
    unsigned short* wvb  = f1 + (size_t)BS * IM_;
    unsigned short* owb  = wvb + H_ * H_;
    unsigned short* w1b  = owb + H_ * H_;
    unsigned short* w2b  = w1b + IM_ * H_;
    int* maskn = (int*)(w2b + H_ * IM_);

    // 1. q vector + mask normalize (fused)
    k_q<<<H_ / 4, 256, 0, stream>>>(dq, in_w, in_b, qv, masks_raw, maskn);
    // 2. weight casts + wqeff (fused)
    k_castw<<<CWB + 36, 256, 0, stream>>>(
        in_w + (size_t)2 * H_ * H_, ow, w1, w2, wvb, owb, w1b, w2b,
        qv, in_w, wqeff);
    // 3. x=tr+pe -> xbf + per-token scores (fused)
    k_xstok<<<BT, 256, 0, stream>>>(token_reps, pe, wqeff, xbf, stok);
    // 4. vtok partials (split-K x4, bf16) -> sum-cast
    gemm_bt<false, true><<<192, 256, 0, stream>>>(
        xbf, wvb, in_b + 2 * H_, pbuf, BT, H_, H_, H_ / 4, 6, 4);
    k_castv4<<<(BT * H_ / 8 + 255) / 256, 256, 0, stream>>>(
        pbuf, (size_t)BT * H_, vtok, BT * H_);
    // 5. attention pooling -> ctx (bf16)
    k_attn<<<BS, 256, 0, stream>>>(stok, vtok, span_ids, maskn, ctx);
    // 6. out_proj partials (split-K x4): 768 blocks
    gemm_bt<false, true><<<768, 256, 0, stream>>>(
        ctx, owb, ob, pbuf, BS, H_, H_, H_ / 4, 6, 4);
    // 7. x1bf = bf16(LN(sum(partials) + dq))
    k_ln<false, false><<<BS, 256, 0, stream>>>(
        pbuf, (size_t)BS * H_, dq, nullptr, g, bt, nullptr, x1bf, nullptr);
    // 8. f1 = bf16(relu(x1 @ w1^T + b1)): 256^2 8-phase, 16x12 = 192 blocks
    gemm256<true, false><<<192, 512, 0, stream>>>(
        x1bf, w1b, b1, f1, BS, IM_, H_, H_, IM_ / 256, 1);
    // 9. FFN2 partials (split-K x4): 256^2 8-phase, 16x3x4 = 192 blocks
    gemm256<false, true><<<192, 512, 0, stream>>>(
        f1, w2b, b2, pbuf, BS, H_, IM_, IM_ / 4, H_ / 256, 4);
    // 10. out = LN(sum(partials) + x1) * mask
    k_ln<true, true><<<BS, 256, 0, stream>>>(
        pbuf, (size_t)BS * H_, nullptr, x1bf, g, bt, (float*)d_out, nullptr, maskn);
}

// Round 2
// 243.777 us; speedup vs baseline: 1.0023x; 1.0023x over previous
//
#include <hip/hip_runtime.h>
#include <math.h>

// Problem constants
static constexpr int B_  = 2;
static constexpr int T_  = 512;
static constexpr int S_  = 2048;
static constexpr int H_  = 768;
static constexpr int L_  = 32;
static constexpr int NH_ = 12;
static constexpr int HD_ = 64;   // H/NH
static constexpr int IM_ = 3072; // 4*H

typedef __bf16 bf16x8 __attribute__((ext_vector_type(8)));
typedef float  f32x4  __attribute__((ext_vector_type(4)));

__device__ __forceinline__ float bf2f(unsigned short u) {
    return __uint_as_float(((unsigned)u) << 16);
}
__device__ __forceinline__ unsigned short f2bf(float f) {
    unsigned u = __float_as_uint(f);
    u += 0x7fffu + ((u >> 16) & 1u);   // RNE
    return (unsigned short)(u >> 16);
}
__device__ __forceinline__ void gl_lds16(const void* g, void* l) {
    __builtin_amdgcn_global_load_lds((const __attribute__((address_space(1))) void*)g,
                                     (__attribute__((address_space(3))) void*)l, 16, 0, 0);
}

// ---------------------------------------------------------------------------
// k_q: q[i] = dq . Wq[i,:] + bq[i], one wave per row.
// Block 0 additionally normalizes span_masks (int32 vs packed-byte autodetect).
__global__ void k_q(const float* __restrict__ dq, const float* __restrict__ w,
                    const float* __restrict__ b, float* __restrict__ q,
                    const int* __restrict__ raw, int* __restrict__ mout) {
    int wv = threadIdx.x >> 6, lane = threadIdx.x & 63;
    int i = blockIdx.x * 4 + wv;
    const float* row = w + (size_t)i * H_;
    float acc = 0.f;
#pragma unroll
    for (int k = 0; k < 12; ++k) acc += dq[lane + 64 * k] * row[lane + 64 * k];
    for (int m = 32; m; m >>= 1) acc += __shfl_xor(acc, m, 64);
    if (lane == 0) q[i] = acc + b[i];
    if (blockIdx.x == 0) {
        __shared__ int bad;
        if (threadIdx.x == 0) bad = 0;
        __syncthreads();
        for (int t = threadIdx.x; t < 1024; t += 256) {
            int v = raw[t];
            if (v != 0 && v != 1) bad = 1;      // benign race
        }
        __syncthreads();
        int byte_layout = bad;
        const unsigned char* rb = (const unsigned char*)raw;
        for (int t = threadIdx.x; t < B_ * S_; t += 256)
            mout[t] = byte_layout ? (int)rb[t] : raw[t];
    }
}

// Fused: weight casts (blocks < CWB) + Wq_eff (blocks >= CWB).
static constexpr int CWB = 2880;   // = (2*H*H + 2*IM*H)/8/256
__global__ void k_castw(const float* __restrict__ s0, const float* __restrict__ s1,
                        const float* __restrict__ s2, const float* __restrict__ s3,
                        unsigned short* __restrict__ d0, unsigned short* __restrict__ d1,
                        unsigned short* __restrict__ d2, unsigned short* __restrict__ d3,
                        const float* __restrict__ q, const float* __restrict__ wk,
                        float* __restrict__ wq) {
    if (blockIdx.x >= CWB) {
        int i = (blockIdx.x - CWB) * 256 + threadIdx.x;   // 36*256 = 9216 exact
        int n = i / H_, hh = i % H_;
        float acc = 0.f;
        for (int d = 0; d < HD_; ++d)
            acc += q[n * HD_ + d] * wk[(size_t)(H_ + n * HD_ + d) * H_ + hh];
        wq[i] = acc;
        return;
    }
    const long n0 = (long)H_ * H_, n2 = (long)IM_ * H_;
    long gid = (long)(blockIdx.x * 256 + threadIdx.x) * 8;
    const float* s; unsigned short* d; long off;
    if (gid < n0)                { s = s0; d = d0; off = gid; }
    else if (gid < 2 * n0)       { s = s1; d = d1; off = gid - n0; }
    else if (gid < 2 * n0 + n2)  { s = s2; d = d2; off = gid - 2 * n0; }
    else                         { s = s3; d = d3; off = gid - 2 * n0 - n2; }
    float4 f0 = *(const float4*)(s + off);
    float4 f1 = *(const float4*)(s + off + 4);
    uint4 o;
    o.x = (unsigned)f2bf(f0.x) | ((unsigned)f2bf(f0.y) << 16);
    o.y = (unsigned)f2bf(f0.z) | ((unsigned)f2bf(f0.w) << 16);
    o.z = (unsigned)f2bf(f1.x) | ((unsigned)f2bf(f1.y) << 16);
    o.w = (unsigned)f2bf(f1.z) | ((unsigned)f2bf(f1.w) << 16);
    *(uint4*)(d + off) = o;
}

// Fused addpe + stok: one block per token row bt.
__global__ void k_xstok(const float* __restrict__ tr, const float* __restrict__ pe,
                        const float* __restrict__ wq,
                        unsigned short* __restrict__ xbf, float* __restrict__ stok) {
    __shared__ float sx[H_];
    int bt = blockIdx.x, tid = threadIdx.x;
    const float* trow = tr + (size_t)bt * H_;
    const float* prow = pe + (size_t)(bt % T_) * H_;
    if (tid < 192) {
        int h0 = tid * 4;
        float4 a = *(const float4*)(trow + h0);
        float4 p = *(const float4*)(prow + h0);
        float v0 = a.x + p.x, v1 = a.y + p.y, v2 = a.z + p.z, v3 = a.w + p.w;
        sx[h0] = v0; sx[h0 + 1] = v1; sx[h0 + 2] = v2; sx[h0 + 3] = v3;
        uint2 o;
        o.x = (unsigned)f2bf(v0) | ((unsigned)f2bf(v1) << 16);
        o.y = (unsigned)f2bf(v2) | ((unsigned)f2bf(v3) << 16);
        *(uint2*)(xbf + (size_t)bt * H_ + h0) = o;
    }
    __syncthreads();
    int lane = tid & 63, w = tid >> 6;
    float xv[12];
#pragma unroll
    for (int k = 0; k < 12; ++k) xv[k] = sx[lane + 64 * k];
#pragma unroll
    for (int hh = 0; hh < 3; ++hh) {
        int n = w * 3 + hh;
        const float* wr = wq + (size_t)n * H_;
        float acc = 0.f;
#pragma unroll
        for (int k = 0; k < 12; ++k) acc += xv[k] * wr[lane + 64 * k];
        for (int m = 32; m; m >>= 1) acc += __shfl_xor(acc, m, 64);
        if (lane == 0) stok[bt * NH_ + n] = acc;
    }
}

// sum of 4 bf16 partial buffers -> bf16, 8 elems/thread
__global__ void k_castv4(const unsigned short* __restrict__ p, size_t pstr,
                         unsigned short* __restrict__ dst, int n) {
    int i = (blockIdx.x * 256 + threadIdx.x) * 8;
    if (i >= n) return;
    float a[8] = {};
#pragma unroll
    for (int z = 0; z < 4; ++z) {
        uint4 u = *(const uint4*)(p + z * pstr + i);
        a[0] += bf2f((unsigned short)(u.x & 0xffff));
        a[1] += bf2f((unsigned short)(u.x >> 16));
        a[2] += bf2f((unsigned short)(u.y & 0xffff));
        a[3] += bf2f((unsigned short)(u.y >> 16));
        a[4] += bf2f((unsigned short)(u.z & 0xffff));
        a[5] += bf2f((unsigned short)(u.z >> 16));
        a[6] += bf2f((unsigned short)(u.w & 0xffff));
        a[7] += bf2f((unsigned short)(u.w >> 16));
    }
    uint4 o;
    o.x = (unsigned)f2bf(a[0]) | ((unsigned)f2bf(a[1]) << 16);
    o.y = (unsigned)f2bf(a[2]) | ((unsigned)f2bf(a[3]) << 16);
    o.z = (unsigned)f2bf(a[4]) | ((unsigned)f2bf(a[5]) << 16);
    o.w = (unsigned)f2bf(a[6]) | ((unsigned)f2bf(a[7]) << 16);
    *(uint4*)(dst + i) = o;
}

// ---------------------------------------------------------------------------
// bf16 MFMA GEMM, 2-phase double-buffered (T3-minimum): 128x128 tile, BK=32,
// 32 KB LDS (>=3 blocks/CU at our grids), stage NEXT tile before computing
// CURRENT, s_waitcnt vmcnt(4) + raw barriers (no vmcnt(0) drain in loop).
// Same staging geometry / XOR swizzle / fragment reads / epilogue as the
// verified R11 gemm_bt core.
#define STG2(c_, k0e_) do {                                                   \
    gl_lds16(agp + (k0e_), lA + (c_) * 4096);                                 \
    gl_lds16(agp + (size_t)16 * K + (k0e_), lA + (c_) * 4096 + 512);          \
    gl_lds16(bgp + (k0e_), lB + (c_) * 4096);                                 \
    gl_lds16(bgp + (size_t)16 * K + (k0e_), lB + (c_) * 4096 + 512);          \
} while (0)

template <bool RELU, bool SPLIT>
__device__ __forceinline__
void gemm_db_body(const unsigned short* __restrict__ A, const unsigned short* __restrict__ W,
                  const float* __restrict__ bias, unsigned short* __restrict__ Cout,
                  int M, int N, int K, int kLen, int TX, int SP) {
    __shared__ unsigned short As[2][4096];    // 2 x (128 rows x 32 cols) = 16 KB
    __shared__ unsigned short Bs[2][4096];
    // XCD-pinned block swizzle: all TX x-tiles of a (y,z) group on one XCD
    const int qx = blockIdx.x & 7, t = blockIdx.x >> 3;
    const int gi = t / TX, x = t - gi * TX;
    const int g = gi * 8 + qx;
    int y, z;
    if (SPLIT) { y = g / SP; z = g - y * SP; } else { y = g; z = 0; }
    const int bm = y * 128, bn = x * 128;
    const int kOff = z * kLen;

    const int tid = threadIdx.x, lane = tid & 63, wid = tid >> 6;   // 0..3
    const int wm = (wid >> 1) * 64, wn = (wid & 1) * 64;
    // staging: wave w stages rows [32w,32w+32) of A and B (2x 1KB each).
    const int r16 = lane >> 2, c4 = lane & 3;
    const int swc = (c4 ^ ((r16 >> 1) & 3)) * 8;       // element offset in row
    const unsigned short* agp = A + (size_t)(bm + wid * 32 + r16) * K + kOff + swc;
    const unsigned short* bgp = W + (size_t)(bn + wid * 32 + r16) * K + kOff + swc;
    unsigned short* lA = &As[0][0] + wid * 1024;       // wave-uniform bases
    unsigned short* lB = &Bs[0][0] + wid * 1024;

    f32x4 acc[4][4];
#pragma unroll
    for (int i = 0; i < 4; ++i)
#pragma unroll
        for (int j = 0; j < 4; ++j) acc[i][j] = f32x4{0.f, 0.f, 0.f, 0.f};

    const int mrow = lane & 15;
    const int q4 = lane >> 4;                          // frag chunk 0..3
    const int sw = (q4 ^ ((mrow >> 1) & 3)) * 8;       // same for all i/j tiles
    const int NIT = kLen >> 5;

    STG2(0, 0);                                        // prologue: tile 0 -> buf0
    for (int it = 0; it < NIT; ++it) {
        const int cur = it & 1;
        int nk = it + 1; if (nk >= NIT) nk = NIT - 1;  // clamp: garbage re-stage
        STG2(cur ^ 1, nk << 5);                        // prefetch next tile
        asm volatile("s_waitcnt vmcnt(4)" ::: "memory");  // cur's 4 loads landed
        __builtin_amdgcn_s_barrier();
        __builtin_amdgcn_sched_barrier(0);
        const unsigned short* Ac = &As[cur][0];
        const unsigned short* Bc = &Bs[cur][0];
        bf16x8 af[4], bfr[4];
#pragma unroll
        for (int i = 0; i < 4; ++i)
            af[i] = *(const bf16x8*)(Ac + (wm + i * 16 + mrow) * 32 + sw);
#pragma unroll
        for (int j = 0; j < 4; ++j)
            bfr[j] = *(const bf16x8*)(Bc + (wn + j * 16 + mrow) * 32 + sw);
        asm volatile("s_waitcnt lgkmcnt(0)" ::: "memory");
        __builtin_amdgcn_sched_barrier(0);
#pragma unroll
        for (int i = 0; i < 4; ++i)
#pragma unroll
            for (int j = 0; j < 4; ++j)
                acc[i][j] = __builtin_amdgcn_mfma_f32_16x16x32_bf16(af[i], bfr[j], acc[i][j], 0, 0, 0);
        __builtin_amdgcn_s_barrier();                  // readers done before overwrite
        __builtin_amdgcn_sched_barrier(0);
    }
    asm volatile("s_waitcnt vmcnt(0)" ::: "memory");   // drain tail DMA before exit

    // epilogue: C/D layout col=lane&15, row=(lane>>4)*4+reg (verified m89/m91)
    const bool addb = !SPLIT || z == 0;
    unsigned short* outp = SPLIT ? Cout + (size_t)z * M * N : Cout;
    const int lr = (lane >> 4) * 4, lc = lane & 15;
#pragma unroll
    for (int j = 0; j < 4; ++j) {
        int col = bn + wn + j * 16 + lc;
        float bv = addb ? bias[col] : 0.f;
#pragma unroll
        for (int i = 0; i < 4; ++i) {
            int row0 = bm + wm + i * 16 + lr;
#pragma unroll
            for (int r = 0; r < 4; ++r) {
                float v = acc[i][j][r] + bv;
                if (RELU) v = fmaxf(v, 0.f);
                outp[(size_t)(row0 + r) * N + col] = f2bf(v);
            }
        }
    }
}

// Named shells so rocprof attributes each step unambiguously.
__global__ __launch_bounds__(256)
void g2_vtok(const unsigned short* A, const unsigned short* W, const float* bias,
             unsigned short* Cout, int M, int N, int K, int kLen, int TX, int SP) {
    gemm_db_body<false, true>(A, W, bias, Cout, M, N, K, kLen, TX, SP);
}
__global__ __launch_bounds__(256)
void g2_oproj(const unsigned short* A, const unsigned short* W, const float* bias,
              unsigned short* Cout, int M, int N, int K, int kLen, int TX, int SP) {
    gemm_db_body<false, true>(A, W, bias, Cout, M, N, K, kLen, TX, SP);
}
__global__ __launch_bounds__(256)
void g2_ffn1(const unsigned short* A, const unsigned short* W, const float* bias,
             unsigned short* Cout, int M, int N, int K, int kLen, int TX, int SP) {
    gemm_db_body<true, false>(A, W, bias, Cout, M, N, K, kLen, TX, SP);
}

// ---------------------------------------------------------------------------
// 256x256 8-phase counted-vmcnt GEMM (m201 template) — kept on step 9 only,
// under a distinct name, as the A/B arm vs the 2-phase kernel.
// See round-1 notes for the stage schedule / region-safety proof.
#define STG(gp_, lp_, h_, kt_) do {                                           \
    const unsigned short* _g = (gp_) + (size_t)((h_) * 128) * K + (kt_) * 64; \
    unsigned short* _l = (lp_) + (h_) * (128 * 64);                           \
    gl_lds16(_g, _l);                                                         \
    gl_lds16(_g + (size_t)8 * K, _l + 8 * 64);                                \
} while (0)

#define LDF(dst_, mat_, rowoff_, kk_)                                         \
    dst_ = *(const bf16x8*)((const char*)(mat_) + (rowoff_) * 128 + rbase +   \
                            ((kk_) ? c1 : c0))

#define RD_A(mat_, base_) do {                                                \
    LDF(a_[0][0], mat_, (base_) + 0,  0); LDF(a_[0][1], mat_, (base_) + 0,  1); \
    LDF(a_[1][0], mat_, (base_) + 16, 0); LDF(a_[1][1], mat_, (base_) + 16, 1); \
    LDF(a_[2][0], mat_, (base_) + 32, 0); LDF(a_[2][1], mat_, (base_) + 32, 1); \
    LDF(a_[3][0], mat_, (base_) + 48, 0); LDF(a_[3][1], mat_, (base_) + 48, 1); \
} while (0)

#define RD_B(dst_, mat_, base_) do {                                          \
    LDF(dst_[0][0], mat_, (base_) + 0,  0); LDF(dst_[0][1], mat_, (base_) + 0,  1); \
    LDF(dst_[1][0], mat_, (base_) + 16, 0); LDF(dst_[1][1], mat_, (base_) + 16, 1); \
} while (0)

#define QPH(MH_, NH_, B_) do {                                                \
    _Pragma("unroll")                                                         \
    for (int m_ = 0; m_ < 4; ++m_) {                                          \
        _Pragma("unroll")                                                     \
        for (int n_ = 0; n_ < 2; ++n_) {                                      \
            f32x4 c_ = acc[(MH_) * 4 + m_][(NH_) * 2 + n_];                   \
            c_ = __builtin_amdgcn_mfma_f32_16x16x32_bf16(a_[m_][0], B_[n_][0], c_, 0, 0, 0); \
            c_ = __builtin_amdgcn_mfma_f32_16x16x32_bf16(a_[m_][1], B_[n_][1], c_, 0, 0, 0); \
            acc[(MH_) * 4 + m_][(NH_) * 2 + n_] = c_;                         \
        }                                                                     \
    }                                                                         \
} while (0)

#define PH_MID do {                                                           \
    __builtin_amdgcn_s_barrier();                                             \
    asm volatile("s_waitcnt lgkmcnt(0)" ::: "memory");                        \
    __builtin_amdgcn_sched_barrier(0);                                        \
    __builtin_amdgcn_s_setprio(1);                                            \
} while (0)

#define PH_END do {                                                           \
    __builtin_amdgcn_s_setprio(0);                                            \
    __builtin_amdgcn_s_barrier();                                             \
    __builtin_amdgcn_sched_barrier(0);                                        \
} while (0)

#define PH_ENDV do {                                                          \
    __builtin_amdgcn_s_setprio(0);                                            \
    asm volatile("s_waitcnt vmcnt(4)" ::: "memory");                          \
    __builtin_amdgcn_s_barrier();                                             \
    __builtin_amdgcn_sched_barrier(0);                                        \
} while (0)

__global__ __launch_bounds__(512)
void g8_ffn2(const unsigned short* __restrict__ A, const unsigned short* __restrict__ W,
             const float* __restrict__ bias, unsigned short* __restrict__ Cout,
             int M, int N, int K, int kLen, int NTt, int SP) {
    constexpr bool RELU = false, SPLIT = true;
    __shared__ unsigned short lds[4][256 * 64];
    (void)SP;
    const int MT = M >> 8;
    int bid = blockIdx.x;
    int z = 0, rem = bid;
    if (SPLIT) { int tpz = MT * NTt; z = bid / tpz; rem = bid - z * tpz; }
    const int y = rem / NTt, x = rem - y * NTt;
    const int bm = y * 256, bn = x * 256;
    const int kOff = z * kLen;
    const int NT = kLen >> 6;          // K-tiles of 64
    const int NIT2 = NT >> 1;

    const int tid = threadIdx.x, lane = tid & 63, wid = tid >> 6;   // 0..7
    const int wm = (wid >> 2) * 128, wn = (wid & 3) * 64;
    const int mrow = lane & 15, q4 = lane >> 4;
    const int rbase = mrow * 128;                                   // read row byte base
    const int c0 = (q4 ^ (mrow & 7)) * 16;                          // kk=0 chunk byte
    const int c1 = ((4 + q4) ^ (mrow & 7)) * 16;                    // kk=1 chunk byte

    const int srow = wid * 16 + (lane >> 3);
    const int gcol = ((lane & 7) ^ ((lane >> 3) & 7)) * 8;
    const unsigned short* agp = A + (size_t)(bm + srow) * K + kOff + gcol;
    const unsigned short* bgp = W + (size_t)(bn + srow) * K + kOff + gcol;
    unsigned short* const aLp0 = lds[0] + wid * 1024;
    unsigned short* const bLp0 = lds[1] + wid * 1024;
    unsigned short* const aLp1 = lds[2] + wid * 1024;
    unsigned short* const bLp1 = lds[3] + wid * 1024;

    f32x4 acc[8][4];
#pragma unroll
    for (int i = 0; i < 8; ++i)
#pragma unroll
        for (int j = 0; j < 4; ++j) acc[i][j] = f32x4{0.f, 0.f, 0.f, 0.f};

    bf16x8 a_[4][2], b0_[2][2], b1_[2][2];

    // Prologue: buf0 complete (8 loads), buf1 B-h0/A-h0 (4 loads).
    STG(agp, aLp0, 0, 0);
    STG(agp, aLp0, 1, 0);
    STG(bgp, bLp0, 0, 0);
    STG(bgp, bLp0, 1, 0);
    STG(bgp, bLp1, 0, 1);
    STG(agp, aLp1, 0, 1);
    asm volatile("s_waitcnt vmcnt(4)" ::: "memory");   // buf0's 8 landed
    __builtin_amdgcn_s_barrier();
    __builtin_amdgcn_sched_barrier(0);

    for (int t = 0; t < NIT2; ++t) {
        const int k1 = 2 * t + 1;
        int k2 = 2 * t + 2; if (k2 > NT - 1) k2 = NT - 1;
        int k3 = 2 * t + 3; if (k3 > NT - 1) k3 = NT - 1;
        // ---- K-tile 2t (buf0) ----
        RD_A(lds[0], wm);
        RD_B(b0_, lds[1], wn);
        STG(bgp, bLp1, 1, k1);
        PH_MID; QPH(0, 0, b0_); PH_END;                  // ph1
        RD_B(b1_, lds[1], wn + 32);
        STG(agp, aLp1, 1, k1);
        PH_MID; QPH(0, 1, b1_); PH_END;                  // ph2
        RD_A(lds[0], wm + 64);
        STG(bgp, bLp0, 0, k2);
        PH_MID; QPH(1, 0, b0_); PH_END;                  // ph3
        STG(agp, aLp0, 0, k2);
        PH_MID; QPH(1, 1, b1_); PH_ENDV;                 // ph4 (buf1 now landed)
        // ---- K-tile 2t+1 (buf1) ----
        RD_A(lds[2], wm);
        RD_B(b0_, lds[3], wn);
        STG(bgp, bLp0, 1, k2);
        PH_MID; QPH(0, 0, b0_); PH_END;                  // ph5
        RD_B(b1_, lds[3], wn + 32);
        STG(agp, aLp0, 1, k2);
        PH_MID; QPH(0, 1, b1_); PH_END;                  // ph6
        RD_A(lds[2], wm + 64);
        STG(bgp, bLp1, 0, k3);
        PH_MID; QPH(1, 0, b0_); PH_END;                  // ph7
        STG(agp, aLp1, 0, k3);
        PH_MID; QPH(1, 1, b1_); PH_ENDV;                 // ph8 (buf0' landed)
    }
    asm volatile("s_waitcnt vmcnt(0)" ::: "memory");     // drain tail DMA

    const bool addb = !SPLIT || z == 0;
    unsigned short* outp = SPLIT ? Cout + (size_t)z * M * N : Cout;
    const int lr = (lane >> 4) * 4, lc = lane & 15;
#pragma unroll
    for (int j = 0; j < 4; ++j) {
        int col = bn + wn + j * 16 + lc;
        float bv = addb ? bias[col] : 0.f;
#pragma unroll
        for (int i = 0; i < 8; ++i) {
            int row0 = bm + wm + i * 16 + lr;
#pragma unroll
            for (int r = 0; r < 4; ++r) {
                float v = acc[i][j][r] + bv;
                if (RELU) v = fmaxf(v, 0.f);
                outp[(size_t)(row0 + r) * N + col] = f2bf(v);
            }
        }
    }
}

// ---------------------------------------------------------------------------
// Per-span attention pooling
__global__ void k_attn(const float* __restrict__ stok, const unsigned short* __restrict__ vtok,
                       const int* __restrict__ span_ids, const int* __restrict__ masks,
                       unsigned short* __restrict__ ctx) {
    int r = blockIdx.x, b = r / S_;
    unsigned short* out = ctx + (size_t)r * H_;
    int tid = threadIdx.x;
    __shared__ float w[NH_][L_];
    __shared__ int idxs[L_];
    __shared__ int s_len;
    if (tid == 0) {
        int m = masks[r];
        int st = span_ids[2 * r], en = span_ids[2 * r + 1];
        int len = m ? (en - st) : 0;
        len = len < 0 ? 0 : (len > L_ ? L_ : len);
        s_len = len;
    }
    __syncthreads();
    int len = s_len;
    if (len == 0) {
        for (int h2 = tid; h2 < H_ / 2; h2 += 256) ((unsigned*)out)[h2] = 0u;
        return;
    }
    if (tid < L_) {
        int p = span_ids[2 * r] + tid;
        idxs[tid] = p < 0 ? 0 : (p > T_ - 1 ? T_ - 1 : p);
    }
    __syncthreads();
    for (int i = tid; i < NH_ * L_; i += 256) {
        int n = i / L_, l = i % L_;
        w[n][l] = (l < len) ? stok[(size_t)(b * T_ + idxs[l]) * NH_ + n] * 0.125f : -INFINITY;
    }
    __syncthreads();
    if (tid < NH_) {
        float mx = -INFINITY;
        for (int l = 0; l < len; ++l) mx = fmaxf(mx, w[tid][l]);
        float sum = 0.f;
        for (int l = 0; l < len; ++l) { float e = __expf(w[tid][l] - mx); w[tid][l] = e; sum += e; }
        float inv = 1.f / sum;
        for (int l = 0; l < len; ++l) w[tid][l] *= inv;
    }
    __syncthreads();
    if (tid < 192) {
        int h0 = tid * 4, n = h0 >> 6;
        float a0 = 0.f, a1 = 0.f, a2 = 0.f, a3 = 0.f;
        for (int l = 0; l < len; ++l) {
            float wl = w[n][l];
            const unsigned short* vr = vtok + (size_t)(b * T_ + idxs[l]) * H_ + h0;
            uint2 u = *(const uint2*)vr;
            a0 += wl * bf2f((unsigned short)(u.x & 0xffff));
            a1 += wl * bf2f((unsigned short)(u.x >> 16));
            a2 += wl * bf2f((unsigned short)(u.y & 0xffff));
            a3 += wl * bf2f((unsigned short)(u.y >> 16));
        }
        uint2 o;
        o.x = (unsigned)f2bf(a0) | ((unsigned)f2bf(a1) << 16);
        o.y = (unsigned)f2bf(a2) | ((unsigned)f2bf(a3) << 16);
        *(uint2*)(out + h0) = o;
    }
}

// ---------------------------------------------------------------------------
// LayerNorm over (sum of 4 bf16 partials + res).
template <bool RESROW, bool MASKOUT>
__global__ void k_ln(const unsigned short* __restrict__ parts, size_t pstr,
                     const float* __restrict__ resf, const unsigned short* __restrict__ resb,
                     const float* __restrict__ g, const float* __restrict__ bt,
                     float* __restrict__ outf, unsigned short* __restrict__ outb,
                     const int* __restrict__ masks) {
    int r = blockIdx.x;
    int tid = threadIdx.x;
    float v[3];
    float lsum = 0.f;
#pragma unroll
    for (int i = 0; i < 3; ++i) {
        int h = tid + 256 * i;
        float s = RESROW ? bf2f(resb[(size_t)r * H_ + h]) : resf[h];
#pragma unroll
        for (int z = 0; z < 4; ++z)
            s += bf2f(parts[z * pstr + (size_t)r * H_ + h]);
        v[i] = s;
        lsum += s;
    }
    __shared__ float sh[256];
    sh[tid] = lsum;
    __syncthreads();
    for (int st = 128; st > 0; st >>= 1) {
        if (tid < st) sh[tid] += sh[tid + st];
        __syncthreads();
    }
    float mean = sh[0] * (1.f / H_);
    __syncthreads();
    float lvar = 0.f;
#pragma unroll
    for (int i = 0; i < 3; ++i) { float d = v[i] - mean; lvar += d * d; }
    sh[tid] = lvar;
    __syncthreads();
    for (int st = 128; st > 0; st >>= 1) {
        if (tid < st) sh[tid] += sh[tid + st];
        __syncthreads();
    }
    float var = sh[0] * (1.f / H_);
    float scale = rsqrtf(var + 1e-5f);
    float mfac = 1.f;
    if (MASKOUT) mfac = masks[r] ? 1.f : 0.f;
#pragma unroll
    for (int i = 0; i < 3; ++i) {
        int h = tid + 256 * i;
        float o = ((v[i] - mean) * scale * g[h] + bt[h]) * mfac;
        if (MASKOUT) outf[(size_t)r * H_ + h] = o;
        else         outb[(size_t)r * H_ + h] = f2bf(o);
    }
}

// ---------------------------------------------------------------------------
extern "C" void kernel_launch(void* const* d_in, const int* in_sizes, int n_in,
                              void* d_out, int out_size, void* d_ws, size_t ws_size,
                              hipStream_t stream) {
    const float* token_reps = (const float*)d_in[0];
    const int*   span_ids   = (const int*)d_in[1];
    const int*   masks_raw  = (const int*)d_in[2];
    const float* pe   = (const float*)d_in[4];
    const float* dq   = (const float*)d_in[5];
    const float* in_w = (const float*)d_in[6];
    const float* in_b = (const float*)d_in[7];
    const float* ow   = (const float*)d_in[8];
    const float* ob   = (const float*)d_in[9];
    const float* g    = (const float*)d_in[10];
    const float* bt   = (const float*)d_in[11];
    const float* w1   = (const float*)d_in[12];
    const float* b1   = (const float*)d_in[13];
    const float* w2   = (const float*)d_in[14];
    const float* b2   = (const float*)d_in[15];

    const int BS = B_ * S_;        // 4096
    const int BT = B_ * T_;        // 1024

    // Workspace layout
    float* fws   = (float*)d_ws;
    float* stok  = fws;                         // 12288
    float* qv    = stok + BT * NH_;             // 768
    float* wqeff = qv + H_;                     // 9216
    unsigned short* us = (unsigned short*)(wqeff + NH_ * H_);
    unsigned short* pbuf = us;                       // 4 * BS*H
    unsigned short* xbf  = pbuf + (size_t)4 * BS * H_;
    unsigned short* vtok = xbf + (size_t)BT * H_;
    unsigned short* ctx  = vtok + (size_t)BT * H_;
    unsigned short* x1bf = ctx + (size_t)BS * H_;
    unsigned short* f1   = x1bf + (size_t)BS * H_;
    unsigned short* wvb  = f1 + (size_t)BS * IM_;
    unsigned short* owb  = wvb + H_ * H_;
    unsigned short* w1b  = owb + H_ * H_;
    unsigned short* w2b  = w1b + IM_ * H_;
    int* maskn = (int*)(w2b + H_ * IM_);

    // 1. q vector + mask normalize (fused)
    k_q<<<H_ / 4, 256, 0, stream>>>(dq, in_w, in_b, qv, masks_raw, maskn);
    // 2. weight casts + wqeff (fused)
    k_castw<<<CWB + 36, 256, 0, stream>>>(
        in_w + (size_t)2 * H_ * H_, ow, w1, w2, wvb, owb, w1b, w2b,
        qv, in_w, wqeff);
    // 3. x=tr+pe -> xbf + per-token scores (fused)
    k_xstok<<<BT, 256, 0, stream>>>(token_reps, pe, wqeff, xbf, stok);
    // 4. vtok partials (split-K x4, bf16) -> sum-cast
    g2_vtok<<<192, 256, 0, stream>>>(
        xbf, wvb, in_b + 2 * H_, pbuf, BT, H_, H_, H_ / 4, 6, 4);
    k_castv4<<<(BT * H_ / 8 + 255) / 256, 256, 0, stream>>>(
        pbuf, (size_t)BT * H_, vtok, BT * H_);
    // 5. attention pooling -> ctx (bf16)
    k_attn<<<BS, 256, 0, stream>>>(stok, vtok, span_ids, maskn, ctx);
    // 6. out_proj partials (split-K x4): 768 blocks
    g2_oproj<<<768, 256, 0, stream>>>(
        ctx, owb, ob, pbuf, BS, H_, H_, H_ / 4, 6, 4);
    // 7. x1bf = bf16(LN(sum(partials) + dq))
    k_ln<false, false><<<BS, 256, 0, stream>>>(
        pbuf, (size_t)BS * H_, dq, nullptr, g, bt, nullptr, x1bf, nullptr);
    // 8. f1 = bf16(relu(x1 @ w1^T + b1)): 2-phase dbuf, 768 blocks (3/CU)
    g2_ffn1<<<768, 256, 0, stream>>>(
        x1bf, w1b, b1, f1, BS, IM_, H_, H_, 24, 1);
    // 9. FFN2 partials (split-K x4): 256^2 8-phase, 192 blocks
    g8_ffn2<<<192, 512, 0, stream>>>(
        f1, w2b, b2, pbuf, BS, H_, IM_, IM_ / 4, 3, 4);
    // 10. out = LN(sum(partials) + x1) * mask
    k_ln<true, true><<<BS, 256, 0, stream>>>(
        pbuf, (size_t)BS * H_, nullptr, x1bf, g, bt, (float*)d_out, nullptr, maskn);
}

// Round 3
// 243.462 us; speedup vs baseline: 1.0036x; 1.0013x over previous
//
#include <hip/hip_runtime.h>
#include <math.h>

// Problem constants
static constexpr int B_  = 2;
static constexpr int T_  = 512;
static constexpr int S_  = 2048;
static constexpr int H_  = 768;
static constexpr int L_  = 32;
static constexpr int NH_ = 12;
static constexpr int HD_ = 64;   // H/NH
static constexpr int IM_ = 3072; // 4*H

typedef __bf16 bf16x8 __attribute__((ext_vector_type(8)));
typedef float  f32x4  __attribute__((ext_vector_type(4)));

__device__ __forceinline__ float bf2f(unsigned short u) {
    return __uint_as_float(((unsigned)u) << 16);
}
__device__ __forceinline__ unsigned short f2bf(float f) {
    unsigned u = __float_as_uint(f);
    u += 0x7fffu + ((u >> 16) & 1u);   // RNE
    return (unsigned short)(u >> 16);
}
__device__ __forceinline__ void gl_lds16(const void* g, void* l) {
    __builtin_amdgcn_global_load_lds((const __attribute__((address_space(1))) void*)g,
                                     (__attribute__((address_space(3))) void*)l, 16, 0, 0);
}

// ---------------------------------------------------------------------------
// k_q: q[i] = dq . Wq[i,:] + bq[i], one wave per row.
// Block 0 additionally normalizes span_masks (int32 vs packed-byte autodetect).
__global__ void k_q(const float* __restrict__ dq, const float* __restrict__ w,
                    const float* __restrict__ b, float* __restrict__ q,
                    const int* __restrict__ raw, int* __restrict__ mout) {
    int wv = threadIdx.x >> 6, lane = threadIdx.x & 63;
    int i = blockIdx.x * 4 + wv;
    const float* row = w + (size_t)i * H_;
    float acc = 0.f;
#pragma unroll
    for (int k = 0; k < 12; ++k) acc += dq[lane + 64 * k] * row[lane + 64 * k];
    for (int m = 32; m; m >>= 1) acc += __shfl_xor(acc, m, 64);
    if (lane == 0) q[i] = acc + b[i];
    if (blockIdx.x == 0) {
        __shared__ int bad;
        if (threadIdx.x == 0) bad = 0;
        __syncthreads();
        for (int t = threadIdx.x; t < 1024; t += 256) {
            int v = raw[t];
            if (v != 0 && v != 1) bad = 1;      // benign race
        }
        __syncthreads();
        int byte_layout = bad;
        const unsigned char* rb = (const unsigned char*)raw;
        for (int t = threadIdx.x; t < B_ * S_; t += 256)
            mout[t] = byte_layout ? (int)rb[t] : raw[t];
    }
}

// Fused: weight casts (blocks < CWB) + Wq_eff (blocks >= CWB).
static constexpr int CWB = 2880;   // = (2*H*H + 2*IM*H)/8/256
__global__ void k_castw(const float* __restrict__ s0, const float* __restrict__ s1,
                        const float* __restrict__ s2, const float* __restrict__ s3,
                        unsigned short* __restrict__ d0, unsigned short* __restrict__ d1,
                        unsigned short* __restrict__ d2, unsigned short* __restrict__ d3,
                        const float* __restrict__ q, const float* __restrict__ wk,
                        float* __restrict__ wq) {
    if (blockIdx.x >= CWB) {
        int i = (blockIdx.x - CWB) * 256 + threadIdx.x;   // 36*256 = 9216 exact
        int n = i / H_, hh = i % H_;
        float acc = 0.f;
        for (int d = 0; d < HD_; ++d)
            acc += q[n * HD_ + d] * wk[(size_t)(H_ + n * HD_ + d) * H_ + hh];
        wq[i] = acc;
        return;
    }
    const long n0 = (long)H_ * H_, n2 = (long)IM_ * H_;
    long gid = (long)(blockIdx.x * 256 + threadIdx.x) * 8;
    const float* s; unsigned short* d; long off;
    if (gid < n0)                { s = s0; d = d0; off = gid; }
    else if (gid < 2 * n0)       { s = s1; d = d1; off = gid - n0; }
    else if (gid < 2 * n0 + n2)  { s = s2; d = d2; off = gid - 2 * n0; }
    else                         { s = s3; d = d3; off = gid - 2 * n0 - n2; }
    float4 f0 = *(const float4*)(s + off);
    float4 f1 = *(const float4*)(s + off + 4);
    uint4 o;
    o.x = (unsigned)f2bf(f0.x) | ((unsigned)f2bf(f0.y) << 16);
    o.y = (unsigned)f2bf(f0.z) | ((unsigned)f2bf(f0.w) << 16);
    o.z = (unsigned)f2bf(f1.x) | ((unsigned)f2bf(f1.y) << 16);
    o.w = (unsigned)f2bf(f1.z) | ((unsigned)f2bf(f1.w) << 16);
    *(uint4*)(d + off) = o;
}

// Fused addpe + stok: one block per token row bt.
__global__ void k_xstok(const float* __restrict__ tr, const float* __restrict__ pe,
                        const float* __restrict__ wq,
                        unsigned short* __restrict__ xbf, float* __restrict__ stok) {
    __shared__ float sx[H_];
    int bt = blockIdx.x, tid = threadIdx.x;
    const float* trow = tr + (size_t)bt * H_;
    const float* prow = pe + (size_t)(bt % T_) * H_;
    if (tid < 192) {
        int h0 = tid * 4;
        float4 a = *(const float4*)(trow + h0);
        float4 p = *(const float4*)(prow + h0);
        float v0 = a.x + p.x, v1 = a.y + p.y, v2 = a.z + p.z, v3 = a.w + p.w;
        sx[h0] = v0; sx[h0 + 1] = v1; sx[h0 + 2] = v2; sx[h0 + 3] = v3;
        uint2 o;
        o.x = (unsigned)f2bf(v0) | ((unsigned)f2bf(v1) << 16);
        o.y = (unsigned)f2bf(v2) | ((unsigned)f2bf(v3) << 16);
        *(uint2*)(xbf + (size_t)bt * H_ + h0) = o;
    }
    __syncthreads();
    int lane = tid & 63, w = tid >> 6;
    float xv[12];
#pragma unroll
    for (int k = 0; k < 12; ++k) xv[k] = sx[lane + 64 * k];
#pragma unroll
    for (int hh = 0; hh < 3; ++hh) {
        int n = w * 3 + hh;
        const float* wr = wq + (size_t)n * H_;
        float acc = 0.f;
#pragma unroll
        for (int k = 0; k < 12; ++k) acc += xv[k] * wr[lane + 64 * k];
        for (int m = 32; m; m >>= 1) acc += __shfl_xor(acc, m, 64);
        if (lane == 0) stok[bt * NH_ + n] = acc;
    }
}

// sum of 4 bf16 partial buffers -> bf16, 8 elems/thread
__global__ void k_castv4(const unsigned short* __restrict__ p, size_t pstr,
                         unsigned short* __restrict__ dst, int n) {
    int i = (blockIdx.x * 256 + threadIdx.x) * 8;
    if (i >= n) return;
    float a[8] = {};
#pragma unroll
    for (int z = 0; z < 4; ++z) {
        uint4 u = *(const uint4*)(p + z * pstr + i);
        a[0] += bf2f((unsigned short)(u.x & 0xffff));
        a[1] += bf2f((unsigned short)(u.x >> 16));
        a[2] += bf2f((unsigned short)(u.y & 0xffff));
        a[3] += bf2f((unsigned short)(u.y >> 16));
        a[4] += bf2f((unsigned short)(u.z & 0xffff));
        a[5] += bf2f((unsigned short)(u.z >> 16));
        a[6] += bf2f((unsigned short)(u.w & 0xffff));
        a[7] += bf2f((unsigned short)(u.w >> 16));
    }
    uint4 o;
    o.x = (unsigned)f2bf(a[0]) | ((unsigned)f2bf(a[1]) << 16);
    o.y = (unsigned)f2bf(a[2]) | ((unsigned)f2bf(a[3]) << 16);
    o.z = (unsigned)f2bf(a[4]) | ((unsigned)f2bf(a[5]) << 16);
    o.w = (unsigned)f2bf(a[6]) | ((unsigned)f2bf(a[7]) << 16);
    *(uint4*)(dst + i) = o;
}

// ---------------------------------------------------------------------------
// bf16 MFMA GEMM, 2-phase double-buffered: 128x128 tile, BK=32, 32 KB LDS
// (>=4 blocks/CU by LDS), stage NEXT tile before computing CURRENT,
// s_waitcnt vmcnt(4) + raw barriers (no vmcnt(0) drain in loop).
// 8-phase 256^2 variant REMOVED: measured 54.6us vs 48 (MfmaUtil 12.8%,
// 1 blk/CU @128KB LDS, NT=12 too short to fill the pipeline) — its regime
// (long-K, deep pipeline) doesn't exist at these shapes.
#define STG2(c_, k0e_) do {                                                   \
    gl_lds16(agp + (k0e_), lA + (c_) * 4096);                                 \
    gl_lds16(agp + (size_t)16 * K + (k0e_), lA + (c_) * 4096 + 512);          \
    gl_lds16(bgp + (k0e_), lB + (c_) * 4096);                                 \
    gl_lds16(bgp + (size_t)16 * K + (k0e_), lB + (c_) * 4096 + 512);          \
} while (0)

template <bool RELU, bool SPLIT>
__device__ __forceinline__
void gemm_db_body(const unsigned short* __restrict__ A, const unsigned short* __restrict__ W,
                  const float* __restrict__ bias, unsigned short* __restrict__ Cout,
                  int M, int N, int K, int kLen, int TX, int SP) {
    __shared__ unsigned short As[2][4096];    // 2 x (128 rows x 32 cols) = 16 KB
    __shared__ unsigned short Bs[2][4096];
    // XCD-pinned block swizzle: all TX x-tiles of a (y,z) group on one XCD
    const int qx = blockIdx.x & 7, t = blockIdx.x >> 3;
    const int gi = t / TX, x = t - gi * TX;
    const int g = gi * 8 + qx;
    int y, z;
    if (SPLIT) { y = g / SP; z = g - y * SP; } else { y = g; z = 0; }
    const int bm = y * 128, bn = x * 128;
    const int kOff = z * kLen;

    const int tid = threadIdx.x, lane = tid & 63, wid = tid >> 6;   // 0..3
    const int wm = (wid >> 1) * 64, wn = (wid & 1) * 64;
    // staging: wave w stages rows [32w,32w+32) of A and B (2x 1KB each).
    const int r16 = lane >> 2, c4 = lane & 3;
    const int swc = (c4 ^ ((r16 >> 1) & 3)) * 8;       // element offset in row
    const unsigned short* agp = A + (size_t)(bm + wid * 32 + r16) * K + kOff + swc;
    const unsigned short* bgp = W + (size_t)(bn + wid * 32 + r16) * K + kOff + swc;
    unsigned short* lA = &As[0][0] + wid * 1024;       // wave-uniform bases
    unsigned short* lB = &Bs[0][0] + wid * 1024;

    f32x4 acc[4][4];
#pragma unroll
    for (int i = 0; i < 4; ++i)
#pragma unroll
        for (int j = 0; j < 4; ++j) acc[i][j] = f32x4{0.f, 0.f, 0.f, 0.f};

    const int mrow = lane & 15;
    const int q4 = lane >> 4;                          // frag chunk 0..3
    const int sw = (q4 ^ ((mrow >> 1) & 3)) * 8;       // same for all i/j tiles
    const int NIT = kLen >> 5;

    STG2(0, 0);                                        // prologue: tile 0 -> buf0
    for (int it = 0; it < NIT; ++it) {
        const int cur = it & 1;
        int nk = it + 1; if (nk >= NIT) nk = NIT - 1;  // clamp: garbage re-stage
        STG2(cur ^ 1, nk << 5);                        // prefetch next tile
        asm volatile("s_waitcnt vmcnt(4)" ::: "memory");  // cur's 4 loads landed
        __builtin_amdgcn_s_barrier();
        __builtin_amdgcn_sched_barrier(0);
        const unsigned short* Ac = &As[cur][0];
        const unsigned short* Bc = &Bs[cur][0];
        bf16x8 af[4], bfr[4];
#pragma unroll
        for (int i = 0; i < 4; ++i)
            af[i] = *(const bf16x8*)(Ac + (wm + i * 16 + mrow) * 32 + sw);
#pragma unroll
        for (int j = 0; j < 4; ++j)
            bfr[j] = *(const bf16x8*)(Bc + (wn + j * 16 + mrow) * 32 + sw);
        asm volatile("s_waitcnt lgkmcnt(0)" ::: "memory");
        __builtin_amdgcn_sched_barrier(0);
#pragma unroll
        for (int i = 0; i < 4; ++i)
#pragma unroll
            for (int j = 0; j < 4; ++j)
                acc[i][j] = __builtin_amdgcn_mfma_f32_16x16x32_bf16(af[i], bfr[j], acc[i][j], 0, 0, 0);
        __builtin_amdgcn_s_barrier();                  // readers done before overwrite
        __builtin_amdgcn_sched_barrier(0);
    }
    asm volatile("s_waitcnt vmcnt(0)" ::: "memory");   // drain tail DMA before exit

    // epilogue: C/D layout col=lane&15, row=(lane>>4)*4+reg (verified m89/m91)
    const bool addb = !SPLIT || z == 0;
    unsigned short* outp = SPLIT ? Cout + (size_t)z * M * N : Cout;
    const int lr = (lane >> 4) * 4, lc = lane & 15;
#pragma unroll
    for (int j = 0; j < 4; ++j) {
        int col = bn + wn + j * 16 + lc;
        float bv = addb ? bias[col] : 0.f;
#pragma unroll
        for (int i = 0; i < 4; ++i) {
            int row0 = bm + wm + i * 16 + lr;
#pragma unroll
            for (int r = 0; r < 4; ++r) {
                float v = acc[i][j][r] + bv;
                if (RELU) v = fmaxf(v, 0.f);
                outp[(size_t)(row0 + r) * N + col] = f2bf(v);
            }
        }
    }
}

// Named shells so rocprof attributes each step unambiguously.
__global__ __launch_bounds__(256)
void g2_vtok(const unsigned short* A, const unsigned short* W, const float* bias,
             unsigned short* Cout, int M, int N, int K, int kLen, int TX, int SP) {
    gemm_db_body<false, true>(A, W, bias, Cout, M, N, K, kLen, TX, SP);
}
__global__ __launch_bounds__(256)
void g2_oproj(const unsigned short* A, const unsigned short* W, const float* bias,
              unsigned short* Cout, int M, int N, int K, int kLen, int TX, int SP) {
    gemm_db_body<false, true>(A, W, bias, Cout, M, N, K, kLen, TX, SP);
}
__global__ __launch_bounds__(256)
void g2_ffn1(const unsigned short* A, const unsigned short* W, const float* bias,
             unsigned short* Cout, int M, int N, int K, int kLen, int TX, int SP) {
    gemm_db_body<true, false>(A, W, bias, Cout, M, N, K, kLen, TX, SP);
}
__global__ __launch_bounds__(256)
void g2_ffn2(const unsigned short* A, const unsigned short* W, const float* bias,
             unsigned short* Cout, int M, int N, int K, int kLen, int TX, int SP) {
    gemm_db_body<false, true>(A, W, bias, Cout, M, N, K, kLen, TX, SP);
}

// ---------------------------------------------------------------------------
// Per-span attention pooling
__global__ void k_attn(const float* __restrict__ stok, const unsigned short* __restrict__ vtok,
                       const int* __restrict__ span_ids, const int* __restrict__ masks,
                       unsigned short* __restrict__ ctx) {
    int r = blockIdx.x, b = r / S_;
    unsigned short* out = ctx + (size_t)r * H_;
    int tid = threadIdx.x;
    __shared__ float w[NH_][L_];
    __shared__ int idxs[L_];
    __shared__ int s_len;
    if (tid == 0) {
        int m = masks[r];
        int st = span_ids[2 * r], en = span_ids[2 * r + 1];
        int len = m ? (en - st) : 0;
        len = len < 0 ? 0 : (len > L_ ? L_ : len);
        s_len = len;
    }
    __syncthreads();
    int len = s_len;
    if (len == 0) {
        for (int h2 = tid; h2 < H_ / 2; h2 += 256) ((unsigned*)out)[h2] = 0u;
        return;
    }
    if (tid < L_) {
        int p = span_ids[2 * r] + tid;
        idxs[tid] = p < 0 ? 0 : (p > T_ - 1 ? T_ - 1 : p);
    }
    __syncthreads();
    for (int i = tid; i < NH_ * L_; i += 256) {
        int n = i / L_, l = i % L_;
        w[n][l] = (l < len) ? stok[(size_t)(b * T_ + idxs[l]) * NH_ + n] * 0.125f : -INFINITY;
    }
    __syncthreads();
    if (tid < NH_) {
        float mx = -INFINITY;
        for (int l = 0; l < len; ++l) mx = fmaxf(mx, w[tid][l]);
        float sum = 0.f;
        for (int l = 0; l < len; ++l) { float e = __expf(w[tid][l] - mx); w[tid][l] = e; sum += e; }
        float inv = 1.f / sum;
        for (int l = 0; l < len; ++l) w[tid][l] *= inv;
    }
    __syncthreads();
    if (tid < 192) {
        int h0 = tid * 4, n = h0 >> 6;
        float a0 = 0.f, a1 = 0.f, a2 = 0.f, a3 = 0.f;
        for (int l = 0; l < len; ++l) {
            float wl = w[n][l];
            const unsigned short* vr = vtok + (size_t)(b * T_ + idxs[l]) * H_ + h0;
            uint2 u = *(const uint2*)vr;
            a0 += wl * bf2f((unsigned short)(u.x & 0xffff));
            a1 += wl * bf2f((unsigned short)(u.x >> 16));
            a2 += wl * bf2f((unsigned short)(u.y & 0xffff));
            a3 += wl * bf2f((unsigned short)(u.y >> 16));
        }
        uint2 o;
        o.x = (unsigned)f2bf(a0) | ((unsigned)f2bf(a1) << 16);
        o.y = (unsigned)f2bf(a2) | ((unsigned)f2bf(a3) << 16);
        *(uint2*)(out + h0) = o;
    }
}

// ---------------------------------------------------------------------------
// LayerNorm over (sum of ZN bf16 partials + res).
template <bool RESROW, bool MASKOUT, int ZN>
__global__ void k_ln(const unsigned short* __restrict__ parts, size_t pstr,
                     const float* __restrict__ resf, const unsigned short* __restrict__ resb,
                     const float* __restrict__ g, const float* __restrict__ bt,
                     float* __restrict__ outf, unsigned short* __restrict__ outb,
                     const int* __restrict__ masks) {
    int r = blockIdx.x;
    int tid = threadIdx.x;
    float v[3];
    float lsum = 0.f;
#pragma unroll
    for (int i = 0; i < 3; ++i) {
        int h = tid + 256 * i;
        float s = RESROW ? bf2f(resb[(size_t)r * H_ + h]) : resf[h];
#pragma unroll
        for (int z = 0; z < ZN; ++z)
            s += bf2f(parts[z * pstr + (size_t)r * H_ + h]);
        v[i] = s;
        lsum += s;
    }
    __shared__ float sh[256];
    sh[tid] = lsum;
    __syncthreads();
    for (int st = 128; st > 0; st >>= 1) {
        if (tid < st) sh[tid] += sh[tid + st];
        __syncthreads();
    }
    float mean = sh[0] * (1.f / H_);
    __syncthreads();
    float lvar = 0.f;
#pragma unroll
    for (int i = 0; i < 3; ++i) { float d = v[i] - mean; lvar += d * d; }
    sh[tid] = lvar;
    __syncthreads();
    for (int st = 128; st > 0; st >>= 1) {
        if (tid < st) sh[tid] += sh[tid + st];
        __syncthreads();
    }
    float var = sh[0] * (1.f / H_);
    float scale = rsqrtf(var + 1e-5f);
    float mfac = 1.f;
    if (MASKOUT) mfac = masks[r] ? 1.f : 0.f;
#pragma unroll
    for (int i = 0; i < 3; ++i) {
        int h = tid + 256 * i;
        float o = ((v[i] - mean) * scale * g[h] + bt[h]) * mfac;
        if (MASKOUT) outf[(size_t)r * H_ + h] = o;
        else         outb[(size_t)r * H_ + h] = f2bf(o);
    }
}

// ---------------------------------------------------------------------------
extern "C" void kernel_launch(void* const* d_in, const int* in_sizes, int n_in,
                              void* d_out, int out_size, void* d_ws, size_t ws_size,
                              hipStream_t stream) {
    const float* token_reps = (const float*)d_in[0];
    const int*   span_ids   = (const int*)d_in[1];
    const int*   masks_raw  = (const int*)d_in[2];
    const float* pe   = (const float*)d_in[4];
    const float* dq   = (const float*)d_in[5];
    const float* in_w = (const float*)d_in[6];
    const float* in_b = (const float*)d_in[7];
    const float* ow   = (const float*)d_in[8];
    const float* ob   = (const float*)d_in[9];
    const float* g    = (const float*)d_in[10];
    const float* bt   = (const float*)d_in[11];
    const float* w1   = (const float*)d_in[12];
    const float* b1   = (const float*)d_in[13];
    const float* w2   = (const float*)d_in[14];
    const float* b2   = (const float*)d_in[15];

    const int BS = B_ * S_;        // 4096
    const int BT = B_ * T_;        // 1024

    // Workspace layout
    float* fws   = (float*)d_ws;
    float* stok  = fws;                         // 12288
    float* qv    = stok + BT * NH_;             // 768
    float* wqeff = qv + H_;                     // 9216
    unsigned short* us = (unsigned short*)(wqeff + NH_ * H_);
    unsigned short* pbuf = us;                       // 4 * BS*H
    unsigned short* xbf  = pbuf + (size_t)4 * BS * H_;
    unsigned short* vtok = xbf + (size_t)BT * H_;
    unsigned short* ctx  = vtok + (size_t)BT * H_;
    unsigned short* x1bf = ctx + (size_t)BS * H_;
    unsigned short* f1   = x1bf + (size_t)BS * H_;
    unsigned short* wvb  = f1 + (size_t)BS * IM_;
    unsigned short* owb  = wvb + H_ * H_;
    unsigned short* w1b  = owb + H_ * H_;
    unsigned short* w2b  = w1b + IM_ * H_;
    int* maskn = (int*)(w2b + H_ * IM_);

    // 1. q vector + mask normalize (fused)
    k_q<<<H_ / 4, 256, 0, stream>>>(dq, in_w, in_b, qv, masks_raw, maskn);
    // 2. weight casts + wqeff (fused)
    k_castw<<<CWB + 36, 256, 0, stream>>>(
        in_w + (size_t)2 * H_ * H_, ow, w1, w2, wvb, owb, w1b, w2b,
        qv, in_w, wqeff);
    // 3. x=tr+pe -> xbf + per-token scores (fused)
    k_xstok<<<BT, 256, 0, stream>>>(token_reps, pe, wqeff, xbf, stok);
    // 4. vtok partials (split-K x4, bf16) -> sum-cast
    g2_vtok<<<192, 256, 0, stream>>>(
        xbf, wvb, in_b + 2 * H_, pbuf, BT, H_, H_, H_ / 4, 6, 4);
    k_castv4<<<(BT * H_ / 8 + 255) / 256, 256, 0, stream>>>(
        pbuf, (size_t)BT * H_, vtok, BT * H_);
    // 5. attention pooling -> ctx (bf16)
    k_attn<<<BS, 256, 0, stream>>>(stok, vtok, span_ids, maskn, ctx);
    // 6. out_proj partials (split-K x2): 384 blocks
    g2_oproj<<<384, 256, 0, stream>>>(
        ctx, owb, ob, pbuf, BS, H_, H_, H_ / 2, 6, 2);
    // 7. x1bf = bf16(LN(sum(2 partials) + dq))
    k_ln<false, false, 2><<<BS, 256, 0, stream>>>(
        pbuf, (size_t)BS * H_, dq, nullptr, g, bt, nullptr, x1bf, nullptr);
    // 8. f1 = bf16(relu(x1 @ w1^T + b1)): 2-phase dbuf, 768 blocks (3/CU)
    g2_ffn1<<<768, 256, 0, stream>>>(
        x1bf, w1b, b1, f1, BS, IM_, H_, H_, 24, 1);
    // 9. FFN2 partials (split-K x2): 384 blocks, kLen=1536 (NIT=48)
    g2_ffn2<<<384, 256, 0, stream>>>(
        f1, w2b, b2, pbuf, BS, H_, IM_, IM_ / 2, 6, 2);
    // 10. out = LN(sum(2 partials) + x1) * mask
    k_ln<true, true, 2><<<BS, 256, 0, stream>>>(
        pbuf, (size_t)BS * H_, nullptr, x1bf, g, bt, (float*)d_out, nullptr, maskn);
}

// Round 4
// 241.441 us; speedup vs baseline: 1.0120x; 1.0084x over previous
//
#include <hip/hip_runtime.h>
#include <math.h>

// Problem constants
static constexpr int B_  = 2;
static constexpr int T_  = 512;
static constexpr int S_  = 2048;
static constexpr int H_  = 768;
static constexpr int L_  = 32;
static constexpr int NH_ = 12;
static constexpr int HD_ = 64;   // H/NH
static constexpr int IM_ = 3072; // 4*H

typedef __bf16 bf16x8 __attribute__((ext_vector_type(8)));
typedef float  f32x4  __attribute__((ext_vector_type(4)));

__device__ __forceinline__ float bf2f(unsigned short u) {
    return __uint_as_float(((unsigned)u) << 16);
}
__device__ __forceinline__ unsigned short f2bf(float f) {
    unsigned u = __float_as_uint(f);
    u += 0x7fffu + ((u >> 16) & 1u);   // RNE
    return (unsigned short)(u >> 16);
}
__device__ __forceinline__ void gl_lds16(const void* g, void* l) {
    __builtin_amdgcn_global_load_lds((const __attribute__((address_space(1))) void*)g,
                                     (__attribute__((address_space(3))) void*)l, 16, 0, 0);
}

// ---------------------------------------------------------------------------
// k_q: q[i] = dq . Wq[i,:] + bq[i], one wave per row.
// Block 0 additionally normalizes span_masks (int32 vs packed-byte autodetect).
__global__ void k_q(const float* __restrict__ dq, const float* __restrict__ w,
                    const float* __restrict__ b, float* __restrict__ q,
                    const int* __restrict__ raw, int* __restrict__ mout) {
    int wv = threadIdx.x >> 6, lane = threadIdx.x & 63;
    int i = blockIdx.x * 4 + wv;
    const float* row = w + (size_t)i * H_;
    float acc = 0.f;
#pragma unroll
    for (int k = 0; k < 12; ++k) acc += dq[lane + 64 * k] * row[lane + 64 * k];
    for (int m = 32; m; m >>= 1) acc += __shfl_xor(acc, m, 64);
    if (lane == 0) q[i] = acc + b[i];
    if (blockIdx.x == 0) {
        __shared__ int bad;
        if (threadIdx.x == 0) bad = 0;
        __syncthreads();
        for (int t = threadIdx.x; t < 1024; t += 256) {
            int v = raw[t];
            if (v != 0 && v != 1) bad = 1;      // benign race
        }
        __syncthreads();
        int byte_layout = bad;
        const unsigned char* rb = (const unsigned char*)raw;
        for (int t = threadIdx.x; t < B_ * S_; t += 256)
            mout[t] = byte_layout ? (int)rb[t] : raw[t];
    }
}

// Fused: weight casts (blocks < CWB) + Wq_eff (blocks >= CWB).
static constexpr int CWB = 2880;   // = (2*H*H + 2*IM*H)/8/256
__global__ void k_castw(const float* __restrict__ s0, const float* __restrict__ s1,
                        const float* __restrict__ s2, const float* __restrict__ s3,
                        unsigned short* __restrict__ d0, unsigned short* __restrict__ d1,
                        unsigned short* __restrict__ d2, unsigned short* __restrict__ d3,
                        const float* __restrict__ q, const float* __restrict__ wk,
                        float* __restrict__ wq) {
    if (blockIdx.x >= CWB) {
        int i = (blockIdx.x - CWB) * 256 + threadIdx.x;   // 36*256 = 9216 exact
        int n = i / H_, hh = i % H_;
        float acc = 0.f;
        for (int d = 0; d < HD_; ++d)
            acc += q[n * HD_ + d] * wk[(size_t)(H_ + n * HD_ + d) * H_ + hh];
        wq[i] = acc;
        return;
    }
    const long n0 = (long)H_ * H_, n2 = (long)IM_ * H_;
    long gid = (long)(blockIdx.x * 256 + threadIdx.x) * 8;
    const float* s; unsigned short* d; long off;
    if (gid < n0)                { s = s0; d = d0; off = gid; }
    else if (gid < 2 * n0)       { s = s1; d = d1; off = gid - n0; }
    else if (gid < 2 * n0 + n2)  { s = s2; d = d2; off = gid - 2 * n0; }
    else                         { s = s3; d = d3; off = gid - 2 * n0 - n2; }
    float4 f0 = *(const float4*)(s + off);
    float4 f1 = *(const float4*)(s + off + 4);
    uint4 o;
    o.x = (unsigned)f2bf(f0.x) | ((unsigned)f2bf(f0.y) << 16);
    o.y = (unsigned)f2bf(f0.z) | ((unsigned)f2bf(f0.w) << 16);
    o.z = (unsigned)f2bf(f1.x) | ((unsigned)f2bf(f1.y) << 16);
    o.w = (unsigned)f2bf(f1.z) | ((unsigned)f2bf(f1.w) << 16);
    *(uint4*)(d + off) = o;
}

// Fused addpe + stok: one block per token row bt.
__global__ void k_xstok(const float* __restrict__ tr, const float* __restrict__ pe,
                        const float* __restrict__ wq,
                        unsigned short* __restrict__ xbf, float* __restrict__ stok) {
    __shared__ float sx[H_];
    int bt = blockIdx.x, tid = threadIdx.x;
    const float* trow = tr + (size_t)bt * H_;
    const float* prow = pe + (size_t)(bt % T_) * H_;
    if (tid < 192) {
        int h0 = tid * 4;
        float4 a = *(const float4*)(trow + h0);
        float4 p = *(const float4*)(prow + h0);
        float v0 = a.x + p.x, v1 = a.y + p.y, v2 = a.z + p.z, v3 = a.w + p.w;
        sx[h0] = v0; sx[h0 + 1] = v1; sx[h0 + 2] = v2; sx[h0 + 3] = v3;
        uint2 o;
        o.x = (unsigned)f2bf(v0) | ((unsigned)f2bf(v1) << 16);
        o.y = (unsigned)f2bf(v2) | ((unsigned)f2bf(v3) << 16);
        *(uint2*)(xbf + (size_t)bt * H_ + h0) = o;
    }
    __syncthreads();
    int lane = tid & 63, w = tid >> 6;
    float xv[12];
#pragma unroll
    for (int k = 0; k < 12; ++k) xv[k] = sx[lane + 64 * k];
#pragma unroll
    for (int hh = 0; hh < 3; ++hh) {
        int n = w * 3 + hh;
        const float* wr = wq + (size_t)n * H_;
        float acc = 0.f;
#pragma unroll
        for (int k = 0; k < 12; ++k) acc += xv[k] * wr[lane + 64 * k];
        for (int m = 32; m; m >>= 1) acc += __shfl_xor(acc, m, 64);
        if (lane == 0) stok[bt * NH_ + n] = acc;
    }
}

// sum of 4 bf16 partial buffers -> bf16, 8 elems/thread
__global__ void k_castv4(const unsigned short* __restrict__ p, size_t pstr,
                         unsigned short* __restrict__ dst, int n) {
    int i = (blockIdx.x * 256 + threadIdx.x) * 8;
    if (i >= n) return;
    float a[8] = {};
#pragma unroll
    for (int z = 0; z < 4; ++z) {
        uint4 u = *(const uint4*)(p + z * pstr + i);
        a[0] += bf2f((unsigned short)(u.x & 0xffff));
        a[1] += bf2f((unsigned short)(u.x >> 16));
        a[2] += bf2f((unsigned short)(u.y & 0xffff));
        a[3] += bf2f((unsigned short)(u.y >> 16));
        a[4] += bf2f((unsigned short)(u.z & 0xffff));
        a[5] += bf2f((unsigned short)(u.z >> 16));
        a[6] += bf2f((unsigned short)(u.w & 0xffff));
        a[7] += bf2f((unsigned short)(u.w >> 16));
    }
    uint4 o;
    o.x = (unsigned)f2bf(a[0]) | ((unsigned)f2bf(a[1]) << 16);
    o.y = (unsigned)f2bf(a[2]) | ((unsigned)f2bf(a[3]) << 16);
    o.z = (unsigned)f2bf(a[4]) | ((unsigned)f2bf(a[5]) << 16);
    o.w = (unsigned)f2bf(a[6]) | ((unsigned)f2bf(a[7]) << 16);
    *(uint4*)(dst + i) = o;
}

// ---------------------------------------------------------------------------
// bf16 MFMA GEMM, depth-3 pipelined: 128x128 tile, BK=32, 3 LDS buffers
// (48 KB -> 3 blocks/CU, matches our 3-blocks/CU grids), stage tile it+2
// each iteration, s_waitcnt vmcnt(8) (12 outstanding; oldest 4 = current
// tile's loads). Rationale: measured ~1600 cy/K-iter on the drain-per-iter
// core = full memory-latency serialization; D=2 hides only ~1 compute-phase
// (~400cy) of the ~300-900cy load latency; D=3 gives 2 phases + barrier
// slack. Overwrite safety: tile it+2's buffer was last read at iter it-1,
// whose end barrier precedes the stage in program order.
#define STG3(b_, k0e_) do {                                                   \
    unsigned short* _la = AsB + (b_) * 4096 + wid * 1024;                     \
    unsigned short* _lb = BsB + (b_) * 4096 + wid * 1024;                     \
    gl_lds16(agp + (k0e_), _la);                                              \
    gl_lds16(agp + (size_t)16 * K + (k0e_), _la + 512);                       \
    gl_lds16(bgp + (k0e_), _lb);                                              \
    gl_lds16(bgp + (size_t)16 * K + (k0e_), _lb + 512);                       \
} while (0)

template <bool RELU, bool SPLIT>
__device__ __forceinline__
void gemm_d3_body(const unsigned short* __restrict__ A, const unsigned short* __restrict__ W,
                  const float* __restrict__ bias, unsigned short* __restrict__ Cout,
                  int M, int N, int K, int kLen, int TX, int SP) {
    __shared__ unsigned short As[3][4096];    // 3 x (128 rows x 32 cols) = 24 KB
    __shared__ unsigned short Bs[3][4096];
    unsigned short* const AsB = &As[0][0];
    unsigned short* const BsB = &Bs[0][0];
    // XCD-pinned block swizzle: all TX x-tiles of a (y,z) group on one XCD
    const int qx = blockIdx.x & 7, t = blockIdx.x >> 3;
    const int gi = t / TX, x = t - gi * TX;
    const int g = gi * 8 + qx;
    int y, z;
    if (SPLIT) { y = g / SP; z = g - y * SP; } else { y = g; z = 0; }
    const int bm = y * 128, bn = x * 128;
    const int kOff = z * kLen;

    const int tid = threadIdx.x, lane = tid & 63, wid = tid >> 6;   // 0..3
    const int wm = (wid >> 1) * 64, wn = (wid & 1) * 64;
    // staging: wave w stages rows [32w,32w+32) of A and B (2x 1KB each).
    const int r16 = lane >> 2, c4 = lane & 3;
    const int swc = (c4 ^ ((r16 >> 1) & 3)) * 8;       // element offset in row
    const unsigned short* agp = A + (size_t)(bm + wid * 32 + r16) * K + kOff + swc;
    const unsigned short* bgp = W + (size_t)(bn + wid * 32 + r16) * K + kOff + swc;

    f32x4 acc[4][4];
#pragma unroll
    for (int i = 0; i < 4; ++i)
#pragma unroll
        for (int j = 0; j < 4; ++j) acc[i][j] = f32x4{0.f, 0.f, 0.f, 0.f};

    const int mrow = lane & 15;
    const int q4 = lane >> 4;                          // frag chunk 0..3
    const int sw = (q4 ^ ((mrow >> 1) & 3)) * 8;       // same for all i/j tiles
    const int NIT = kLen >> 5;

    // prologue: tiles 0 and 1 (NIT >= 2 at all our call sites)
    STG3(0, 0);
    STG3(1, 1 << 5);
    int c0 = 0, c1 = 1, c2 = 2;                        // read / mid / stage bufs
    for (int it = 0; it < NIT; ++it) {
        int nk = it + 2; if (nk > NIT - 1) nk = NIT - 1;   // clamp: garbage re-stage
        STG3(c2, nk << 5);                             // prefetch tile it+2
        asm volatile("s_waitcnt vmcnt(8)" ::: "memory");   // tile it's 4 loads landed
        __builtin_amdgcn_s_barrier();
        __builtin_amdgcn_sched_barrier(0);
        const unsigned short* Ac = AsB + c0 * 4096;
        const unsigned short* Bc = BsB + c0 * 4096;
        bf16x8 af[4], bfr[4];
#pragma unroll
        for (int i = 0; i < 4; ++i)
            af[i] = *(const bf16x8*)(Ac + (wm + i * 16 + mrow) * 32 + sw);
#pragma unroll
        for (int j = 0; j < 4; ++j)
            bfr[j] = *(const bf16x8*)(Bc + (wn + j * 16 + mrow) * 32 + sw);
        asm volatile("s_waitcnt lgkmcnt(0)" ::: "memory");
        __builtin_amdgcn_sched_barrier(0);
#pragma unroll
        for (int i = 0; i < 4; ++i)
#pragma unroll
            for (int j = 0; j < 4; ++j)
                acc[i][j] = __builtin_amdgcn_mfma_f32_16x16x32_bf16(af[i], bfr[j], acc[i][j], 0, 0, 0);
        __builtin_amdgcn_s_barrier();                  // readers done before overwrite
        __builtin_amdgcn_sched_barrier(0);
        int tmp = c0; c0 = c1; c1 = c2; c2 = tmp;      // rotate buffers
    }
    asm volatile("s_waitcnt vmcnt(0)" ::: "memory");   // drain tail DMA before exit

    // epilogue: C/D layout col=lane&15, row=(lane>>4)*4+reg (verified m89/m91)
    const bool addb = !SPLIT || z == 0;
    unsigned short* outp = SPLIT ? Cout + (size_t)z * M * N : Cout;
    const int lr = (lane >> 4) * 4, lc = lane & 15;
#pragma unroll
    for (int j = 0; j < 4; ++j) {
        int col = bn + wn + j * 16 + lc;
        float bv = addb ? bias[col] : 0.f;
#pragma unroll
        for (int i = 0; i < 4; ++i) {
            int row0 = bm + wm + i * 16 + lr;
#pragma unroll
            for (int r = 0; r < 4; ++r) {
                float v = acc[i][j][r] + bv;
                if (RELU) v = fmaxf(v, 0.f);
                outp[(size_t)(row0 + r) * N + col] = f2bf(v);
            }
        }
    }
}

// Named shells so rocprof attributes each step unambiguously.
__global__ __launch_bounds__(256)
void g3_vtok(const unsigned short* A, const unsigned short* W, const float* bias,
             unsigned short* Cout, int M, int N, int K, int kLen, int TX, int SP) {
    gemm_d3_body<false, true>(A, W, bias, Cout, M, N, K, kLen, TX, SP);
}
__global__ __launch_bounds__(256)
void g3_oproj(const unsigned short* A, const unsigned short* W, const float* bias,
              unsigned short* Cout, int M, int N, int K, int kLen, int TX, int SP) {
    gemm_d3_body<false, true>(A, W, bias, Cout, M, N, K, kLen, TX, SP);
}
__global__ __launch_bounds__(256)
void g3_ffn1(const unsigned short* A, const unsigned short* W, const float* bias,
             unsigned short* Cout, int M, int N, int K, int kLen, int TX, int SP) {
    gemm_d3_body<true, false>(A, W, bias, Cout, M, N, K, kLen, TX, SP);
}
__global__ __launch_bounds__(256)
void g3_ffn2(const unsigned short* A, const unsigned short* W, const float* bias,
             unsigned short* Cout, int M, int N, int K, int kLen, int TX, int SP) {
    gemm_d3_body<false, true>(A, W, bias, Cout, M, N, K, kLen, TX, SP);
}

// ---------------------------------------------------------------------------
// Per-span attention pooling
__global__ void k_attn(const float* __restrict__ stok, const unsigned short* __restrict__ vtok,
                       const int* __restrict__ span_ids, const int* __restrict__ masks,
                       unsigned short* __restrict__ ctx) {
    int r = blockIdx.x, b = r / S_;
    unsigned short* out = ctx + (size_t)r * H_;
    int tid = threadIdx.x;
    __shared__ float w[NH_][L_];
    __shared__ int idxs[L_];
    __shared__ int s_len;
    if (tid == 0) {
        int m = masks[r];
        int st = span_ids[2 * r], en = span_ids[2 * r + 1];
        int len = m ? (en - st) : 0;
        len = len < 0 ? 0 : (len > L_ ? L_ : len);
        s_len = len;
    }
    __syncthreads();
    int len = s_len;
    if (len == 0) {
        for (int h2 = tid; h2 < H_ / 2; h2 += 256) ((unsigned*)out)[h2] = 0u;
        return;
    }
    if (tid < L_) {
        int p = span_ids[2 * r] + tid;
        idxs[tid] = p < 0 ? 0 : (p > T_ - 1 ? T_ - 1 : p);
    }
    __syncthreads();
    for (int i = tid; i < NH_ * L_; i += 256) {
        int n = i / L_, l = i % L_;
        w[n][l] = (l < len) ? stok[(size_t)(b * T_ + idxs[l]) * NH_ + n] * 0.125f : -INFINITY;
    }
    __syncthreads();
    if (tid < NH_) {
        float mx = -INFINITY;
        for (int l = 0; l < len; ++l) mx = fmaxf(mx, w[tid][l]);
        float sum = 0.f;
        for (int l = 0; l < len; ++l) { float e = __expf(w[tid][l] - mx); w[tid][l] = e; sum += e; }
        float inv = 1.f / sum;
        for (int l = 0; l < len; ++l) w[tid][l] *= inv;
    }
    __syncthreads();
    if (tid < 192) {
        int h0 = tid * 4, n = h0 >> 6;
        float a0 = 0.f, a1 = 0.f, a2 = 0.f, a3 = 0.f;
        for (int l = 0; l < len; ++l) {
            float wl = w[n][l];
            const unsigned short* vr = vtok + (size_t)(b * T_ + idxs[l]) * H_ + h0;
            uint2 u = *(const uint2*)vr;
            a0 += wl * bf2f((unsigned short)(u.x & 0xffff));
            a1 += wl * bf2f((unsigned short)(u.x >> 16));
            a2 += wl * bf2f((unsigned short)(u.y & 0xffff));
            a3 += wl * bf2f((unsigned short)(u.y >> 16));
        }
        uint2 o;
        o.x = (unsigned)f2bf(a0) | ((unsigned)f2bf(a1) << 16);
        o.y = (unsigned)f2bf(a2) | ((unsigned)f2bf(a3) << 16);
        *(uint2*)(out + h0) = o;
    }
}

// ---------------------------------------------------------------------------
// LayerNorm over (sum of ZN bf16 partials + res).
template <bool RESROW, bool MASKOUT, int ZN>
__global__ void k_ln(const unsigned short* __restrict__ parts, size_t pstr,
                     const float* __restrict__ resf, const unsigned short* __restrict__ resb,
                     const float* __restrict__ g, const float* __restrict__ bt,
                     float* __restrict__ outf, unsigned short* __restrict__ outb,
                     const int* __restrict__ masks) {
    int r = blockIdx.x;
    int tid = threadIdx.x;
    float v[3];
    float lsum = 0.f;
#pragma unroll
    for (int i = 0; i < 3; ++i) {
        int h = tid + 256 * i;
        float s = RESROW ? bf2f(resb[(size_t)r * H_ + h]) : resf[h];
#pragma unroll
        for (int z = 0; z < ZN; ++z)
            s += bf2f(parts[z * pstr + (size_t)r * H_ + h]);
        v[i] = s;
        lsum += s;
    }
    __shared__ float sh[256];
    sh[tid] = lsum;
    __syncthreads();
    for (int st = 128; st > 0; st >>= 1) {
        if (tid < st) sh[tid] += sh[tid + st];
        __syncthreads();
    }
    float mean = sh[0] * (1.f / H_);
    __syncthreads();
    float lvar = 0.f;
#pragma unroll
    for (int i = 0; i < 3; ++i) { float d = v[i] - mean; lvar += d * d; }
    sh[tid] = lvar;
    __syncthreads();
    for (int st = 128; st > 0; st >>= 1) {
        if (tid < st) sh[tid] += sh[tid + st];
        __syncthreads();
    }
    float var = sh[0] * (1.f / H_);
    float scale = rsqrtf(var + 1e-5f);
    float mfac = 1.f;
    if (MASKOUT) mfac = masks[r] ? 1.f : 0.f;
#pragma unroll
    for (int i = 0; i < 3; ++i) {
        int h = tid + 256 * i;
        float o = ((v[i] - mean) * scale * g[h] + bt[h]) * mfac;
        if (MASKOUT) outf[(size_t)r * H_ + h] = o;
        else         outb[(size_t)r * H_ + h] = f2bf(o);
    }
}

// ---------------------------------------------------------------------------
extern "C" void kernel_launch(void* const* d_in, const int* in_sizes, int n_in,
                              void* d_out, int out_size, void* d_ws, size_t ws_size,
                              hipStream_t stream) {
    const float* token_reps = (const float*)d_in[0];
    const int*   span_ids   = (const int*)d_in[1];
    const int*   masks_raw  = (const int*)d_in[2];
    const float* pe   = (const float*)d_in[4];
    const float* dq   = (const float*)d_in[5];
    const float* in_w = (const float*)d_in[6];
    const float* in_b = (const float*)d_in[7];
    const float* ow   = (const float*)d_in[8];
    const float* ob   = (const float*)d_in[9];
    const float* g    = (const float*)d_in[10];
    const float* bt   = (const float*)d_in[11];
    const float* w1   = (const float*)d_in[12];
    const float* b1   = (const float*)d_in[13];
    const float* w2   = (const float*)d_in[14];
    const float* b2   = (const float*)d_in[15];

    const int BS = B_ * S_;        // 4096
    const int BT = B_ * T_;        // 1024

    // Workspace layout
    float* fws   = (float*)d_ws;
    float* stok  = fws;                         // 12288
    float* qv    = stok + BT * NH_;             // 768
    float* wqeff = qv + H_;                     // 9216
    unsigned short* us = (unsigned short*)(wqeff + NH_ * H_);
    unsigned short* pbuf = us;                       // 4 * BS*H
    unsigned short* xbf  = pbuf + (size_t)4 * BS * H_;
    unsigned short* vtok = xbf + (size_t)BT * H_;
    unsigned short* ctx  = vtok + (size_t)BT * H_;
    unsigned short* x1bf = ctx + (size_t)BS * H_;
    unsigned short* f1   = x1bf + (size_t)BS * H_;
    unsigned short* wvb  = f1 + (size_t)BS * IM_;
    unsigned short* owb  = wvb + H_ * H_;
    unsigned short* w1b  = owb + H_ * H_;
    unsigned short* w2b  = w1b + IM_ * H_;
    int* maskn = (int*)(w2b + H_ * IM_);

    // 1. q vector + mask normalize (fused)
    k_q<<<H_ / 4, 256, 0, stream>>>(dq, in_w, in_b, qv, masks_raw, maskn);
    // 2. weight casts + wqeff (fused)
    k_castw<<<CWB + 36, 256, 0, stream>>>(
        in_w + (size_t)2 * H_ * H_, ow, w1, w2, wvb, owb, w1b, w2b,
        qv, in_w, wqeff);
    // 3. x=tr+pe -> xbf + per-token scores (fused)
    k_xstok<<<BT, 256, 0, stream>>>(token_reps, pe, wqeff, xbf, stok);
    // 4. vtok partials (split-K x4, bf16) -> sum-cast
    g3_vtok<<<192, 256, 0, stream>>>(
        xbf, wvb, in_b + 2 * H_, pbuf, BT, H_, H_, H_ / 4, 6, 4);
    k_castv4<<<(BT * H_ / 8 + 255) / 256, 256, 0, stream>>>(
        pbuf, (size_t)BT * H_, vtok, BT * H_);
    // 5. attention pooling -> ctx (bf16)
    k_attn<<<BS, 256, 0, stream>>>(stok, vtok, span_ids, maskn, ctx);
    // 6. out_proj partials (split-K x2): 384 blocks
    g3_oproj<<<384, 256, 0, stream>>>(
        ctx, owb, ob, pbuf, BS, H_, H_, H_ / 2, 6, 2);
    // 7. x1bf = bf16(LN(sum(2 partials) + dq))
    k_ln<false, false, 2><<<BS, 256, 0, stream>>>(
        pbuf, (size_t)BS * H_, dq, nullptr, g, bt, nullptr, x1bf, nullptr);
    // 8. f1 = bf16(relu(x1 @ w1^T + b1)): depth-3 pipeline, 768 blocks (3/CU)
    g3_ffn1<<<768, 256, 0, stream>>>(
        x1bf, w1b, b1, f1, BS, IM_, H_, H_, 24, 1);
    // 9. FFN2 partials (split-K x2): 384 blocks, kLen=1536 (NIT=48)
    g3_ffn2<<<384, 256, 0, stream>>>(
        f1, w2b, b2, pbuf, BS, H_, IM_, IM_ / 2, 6, 2);
    // 10. out = LN(sum(2 partials) + x1) * mask
    k_ln<true, true, 2><<<BS, 256, 0, stream>>>(
        pbuf, (size_t)BS * H_, nullptr, x1bf, g, bt, (float*)d_out, nullptr, maskn);
}